// Round 5
// baseline (1984.155 us; speedup 1.0000x reference)
//
#include <hip/hip_runtime.h>

// Problem constants
#define HW     16384      // 128*128
#define NB     8
#define CDIM   192
#define CH3    576
#define NHEADS 4
#define CHH    48
#define NSL2   128        // gram pixel-slices (128 px each)
#define LDP    136        // gram LDS row stride (elems, mult of 8; 68 dwords = 4 mod 32 -> 2-way free)

typedef short  v8s  __attribute__((ext_vector_type(8)));
typedef float  v4f  __attribute__((ext_vector_type(4)));
typedef unsigned short u16x8 __attribute__((ext_vector_type(8)));

__device__ __forceinline__ float bf2f(unsigned short s) {
    return __uint_as_float(((unsigned)s) << 16);
}
__device__ __forceinline__ unsigned short f2bf(float f) {
    unsigned u = __float_as_uint(f);
    return (unsigned short)((u + 0x7fffu + ((u >> 16) & 1u)) >> 16);
}
__device__ __forceinline__ float gelu_f(float x) {
    return 0.5f * x * (1.0f + erff(x * 0.70710678118654752f));
}

// ---------------------------------------------------------------------------
// Weight prep: 4 GEMM mats fp32->bf16 packed; 3 depthwise mats transposed to
// [tap][576] bf16. grid (162, 7)
// ---------------------------------------------------------------------------
__global__ __launch_bounds__(256) void wcvt(const float* __restrict__ s0,
                                            const float* __restrict__ s1,
                                            const float* __restrict__ s2,
                                            const float* __restrict__ s3,
                                            const float* __restrict__ dq,
                                            const float* __restrict__ d1,
                                            const float* __restrict__ d2,
                                            unsigned short* __restrict__ d,
                                            int n0, int n1, int n2, int n3) {
    int y = blockIdx.y;
    if (y < 4) {
        const float* srcs[4] = {s0, s1, s2, s3};
        int cnts[4] = {n0, n1, n2, n3};
        int offs[4] = {0, n0, n0 + n1, n0 + n1 + n2};
        const float* s = srcs[y];
        unsigned short* o = d + offs[y];
        int i = (blockIdx.x * 256 + threadIdx.x) * 8;
        if (i + 8 <= cnts[y]) {
            float4 a = *(const float4*)(s + i);
            float4 b = *(const float4*)(s + i + 4);
            u16x8 u;
            u[0] = f2bf(a.x); u[1] = f2bf(a.y); u[2] = f2bf(a.z); u[3] = f2bf(a.w);
            u[4] = f2bf(b.x); u[5] = f2bf(b.y); u[6] = f2bf(b.z); u[7] = f2bf(b.w);
            *(u16x8*)(o + i) = u;
        }
    } else {
        const float* s = (y == 4) ? dq : (y == 5) ? d1 : d2;
        unsigned short* o = d + (n0 + n1 + n2 + n3) + (y - 4) * 9 * CH3;
        int i = blockIdx.x * 256 + threadIdx.x;
        if (i < 9 * CH3) {
            int tap = i / CH3, c = i - tap * CH3;
            o[i] = f2bf(s[c * 9 + tap]);
        }
    }
}

__global__ __launch_bounds__(256) void zero_f(float* __restrict__ p, int n) {
    int i = blockIdx.x * 256 + threadIdx.x;
    if (i < n) p[i] = 0.f;
}

// ---------------------------------------------------------------------------
// LayerNorm: NCHW fp32 in -> NHWC bf16 out. grid (64, Z)
// ---------------------------------------------------------------------------
__global__ __launch_bounds__(256) void ln_norm(const float* __restrict__ x,
                                               const float* __restrict__ lnw,
                                               const float* __restrict__ lnb,
                                               unsigned short* __restrict__ xn) {
    int p = blockIdx.x * 256 + threadIdx.x;
    int z = blockIdx.y;
    const float* xp = x + (size_t)z * CDIM * HW;
    float s = 0.f, ss = 0.f;
    for (int c = 0; c < CDIM; ++c) {
        float v = xp[(size_t)c * HW + p];
        s += v; ss += v * v;
    }
    float m = s * (1.0f / CDIM);
    float var = ss * (1.0f / CDIM) - m * m;
    float r = 1.0f / sqrtf(var + 1e-5f);
    unsigned short* op = xn + ((size_t)z * HW + p) * CDIM;
    for (int c8 = 0; c8 < CDIM; c8 += 8) {
        u16x8 u;
#pragma unroll
        for (int j = 0; j < 8; ++j)
            u[j] = f2bf((xp[(size_t)(c8 + j) * HW + p] - m) * r * lnw[c8 + j] + lnb[c8 + j]);
        *(u16x8*)(op + c8) = u;
    }
}

// ---------------------------------------------------------------------------
// NHWC GEMM (swapped roles, NO LDS/barriers): out[p][ch] = sum_k X[p][k]*W[ch][k]
// X NHWC bf16 stride K; W bf16 [M][K]. Block 128p x 96ch, 4 waves (2x2),
// wave 64p x 48ch: 4 a-frags x 3 b-frags, 12 MFMA/K-step, all direct global.
// EPI 0: +bias -> bf16; 1: +bias+gelu -> bf16. grid (128, M/96, Z)
// ---------------------------------------------------------------------------
template <int EPI, int K>
__global__ __launch_bounds__(256) void gemm_nhwc(
    const unsigned short* __restrict__ Wb,
    const unsigned short* __restrict__ X,
    const float* __restrict__ bias,
    unsigned short* __restrict__ out, int MS) {
    const int t = threadIdx.x;
    const int p0 = blockIdx.x * 128, M0 = blockIdx.y * 96, z = blockIdx.z;
    const int wid = t >> 6, lane = t & 63, lm = lane & 15, quad = lane >> 4;
    const int wp = (wid & 1) * 64, wc = (wid >> 1) * 48;

    const unsigned short* Xz = X + (size_t)z * HW * K;
    v4f acc[4][3];
#pragma unroll
    for (int i = 0; i < 4; ++i)
#pragma unroll
        for (int j = 0; j < 3; ++j) acc[i][j] = (v4f)0.0f;

    const unsigned short* ar[4];
    const unsigned short* br[3];
#pragma unroll
    for (int i = 0; i < 4; ++i) ar[i] = Xz + (size_t)(p0 + wp + i * 16 + lm) * K + quad * 8;
#pragma unroll
    for (int j = 0; j < 3; ++j) br[j] = Wb + (size_t)(M0 + wc + j * 16 + lm) * K + quad * 8;

#pragma unroll 2
    for (int k0 = 0; k0 < K; k0 += 32) {
        v8s a[4], b[3];
#pragma unroll
        for (int i = 0; i < 4; ++i) a[i] = *(const v8s*)(ar[i] + k0);
#pragma unroll
        for (int j = 0; j < 3; ++j) b[j] = *(const v8s*)(br[j] + k0);
#pragma unroll
        for (int i = 0; i < 4; ++i)
#pragma unroll
            for (int j = 0; j < 3; ++j)
                acc[i][j] = __builtin_amdgcn_mfma_f32_16x16x32_bf16(a[i], b[j], acc[i][j], 0, 0, 0);
    }

    unsigned short* Oz = out + (size_t)z * HW * MS;
#pragma unroll
    for (int i = 0; i < 4; ++i)
#pragma unroll
        for (int j = 0; j < 3; ++j) {
            int ch = M0 + wc + j * 16 + lm;
            float bch = bias[ch];
#pragma unroll
            for (int r = 0; r < 4; ++r) {
                int p = p0 + wp + i * 16 + quad * 4 + r;
                float v = acc[i][j][r] + bch;
                if (EPI == 1) v = gelu_f(v);
                Oz[(size_t)p * MS + ch] = f2bf(v);
            }
        }
}

// ---------------------------------------------------------------------------
// NCHW-output GEMM (classic roles, NO LDS): out[m][p] = sum_k W[m][k]*X[p][k]
// + residual, fp32 NCHW out. Block 64m x 128p, 4 waves (2x2). grid (128,3,Z)
// ---------------------------------------------------------------------------
template <int K>
__global__ __launch_bounds__(256) void gemm_nchw(
    const unsigned short* __restrict__ Wb,
    const unsigned short* __restrict__ X,
    const float* __restrict__ bias,
    const float* __restrict__ res,
    float* __restrict__ outp) {
    const int t = threadIdx.x;
    const int p0 = blockIdx.x * 128, m0 = blockIdx.y * 64, z = blockIdx.z;
    const int wid = t >> 6, lane = t & 63, lm = lane & 15, quad = lane >> 4;
    const int wm = (wid & 1) * 32, wph = (wid >> 1) * 64;

    const unsigned short* Xz = X + (size_t)z * HW * K;
    v4f acc[2][4];
#pragma unroll
    for (int i = 0; i < 2; ++i)
#pragma unroll
        for (int j = 0; j < 4; ++j) acc[i][j] = (v4f)0.0f;

    const unsigned short* ar[2];
    const unsigned short* br[4];
#pragma unroll
    for (int i = 0; i < 2; ++i) ar[i] = Wb + (size_t)(m0 + wm + i * 16 + lm) * K + quad * 8;
#pragma unroll
    for (int j = 0; j < 4; ++j) br[j] = Xz + (size_t)(p0 + wph + j * 16 + lm) * K + quad * 8;

#pragma unroll 2
    for (int k0 = 0; k0 < K; k0 += 32) {
        v8s a[2], b[4];
#pragma unroll
        for (int i = 0; i < 2; ++i) a[i] = *(const v8s*)(ar[i] + k0);
#pragma unroll
        for (int j = 0; j < 4; ++j) b[j] = *(const v8s*)(br[j] + k0);
#pragma unroll
        for (int i = 0; i < 2; ++i)
#pragma unroll
            for (int j = 0; j < 4; ++j)
                acc[i][j] = __builtin_amdgcn_mfma_f32_16x16x32_bf16(a[i], b[j], acc[i][j], 0, 0, 0);
    }

#pragma unroll
    for (int i = 0; i < 2; ++i)
#pragma unroll
        for (int j = 0; j < 4; ++j) {
            int gp = p0 + wph + j * 16 + lm;
#pragma unroll
            for (int r = 0; r < 4; ++r) {
                int gm = m0 + wm + i * 16 + quad * 4 + r;
                size_t oi = (size_t)z * CDIM * HW + (size_t)gm * HW + gp;
                outp[oi] = acc[i][j][r] + bias[gm] + res[oi];
            }
        }
}

// ---------------------------------------------------------------------------
// Depthwise 3x3 + bias + prompt on NHWC 576ch, 8 ch/thread, fused sum-sq
// atomics for q,k channels. grid (64, 72, Z)
// ---------------------------------------------------------------------------
__global__ __launch_bounds__(256) void dwp_nhwc(const unsigned short* __restrict__ in,
                                                const unsigned short* __restrict__ wT,
                                                const float* __restrict__ b1,
                                                const float* __restrict__ prompt,
                                                unsigned short* __restrict__ out,
                                                float* __restrict__ ssbuf) {
    int t = threadIdx.x;
    int px = blockIdx.x * 256 + t;
    int c0 = blockIdx.y * 8;
    int z = blockIdx.z;
    int h = px >> 7, w = px & 127;
    const unsigned short* ip = in + (size_t)z * HW * CH3;
    int pc = c0 % CDIM;
    float acc[8];
#pragma unroll
    for (int j = 0; j < 8; ++j) acc[j] = b1[c0 + j] + prompt[pc + j];
#pragma unroll
    for (int ky = 0; ky < 3; ++ky) {
        int hy = h + ky - 1;
        if ((unsigned)hy >= 128u) continue;
#pragma unroll
        for (int kx = 0; kx < 3; ++kx) {
            int wx = w + kx - 1;
            if ((unsigned)wx >= 128u) continue;
            u16x8 xv = *(const u16x8*)(ip + (size_t)((hy << 7) + wx) * CH3 + c0);
            u16x8 wv = *(const u16x8*)(wT + (ky * 3 + kx) * CH3 + c0);
#pragma unroll
            for (int j = 0; j < 8; ++j) acc[j] = fmaf(bf2f(wv[j]), bf2f(xv[j]), acc[j]);
        }
    }
    u16x8 o;
    float sl[8];
#pragma unroll
    for (int j = 0; j < 8; ++j) {
        unsigned short q = f2bf(acc[j]);
        o[j] = q;
        float vr = bf2f(q);
        sl[j] = vr * vr;
    }
    *(u16x8*)(out + (size_t)z * HW * CH3 + (size_t)px * CH3 + c0) = o;

    if (c0 < 384) {   // q,k channels: accumulate sum-squares
        int wid = t >> 6, lane = t & 63;
#pragma unroll
        for (int j = 0; j < 8; ++j)
            for (int off = 32; off; off >>= 1) sl[j] += __shfl_down(sl[j], off);
        __shared__ float wr[4][8];
        if (lane == 0)
#pragma unroll
            for (int j = 0; j < 8; ++j) wr[wid][j] = sl[j];
        __syncthreads();
        if (t < 8) {
            float s = wr[0][t] + wr[1][t] + wr[2][t] + wr[3][t];
            atomicAdd(&ssbuf[z * 384 + c0 + t], s);
        }
    }
}

// ---------------------------------------------------------------------------
// Gram partials: G[cq][ck] = sum_p q[p][cq]*k[p][ck] per 128-px slice.
// LDS transpose-stage NHWC -> [c][p], then MFMA (waves split p). grid (128,4,Z)
// ---------------------------------------------------------------------------
__global__ __launch_bounds__(256) void gram1(const unsigned short* __restrict__ qkvT,
                                             float* __restrict__ G0p) {
    const int sl = blockIdx.x, hh = blockIdx.y, z = blockIdx.z;
    const int t = threadIdx.x;
    const int wid = t >> 6, lane = t & 63, lm = lane & 15, quad = lane >> 4;

    __shared__ float Gs[4][2304];                       // 36.9 KB, aliased below
    unsigned short* qs = (unsigned short*)&Gs[0][0];    // [48][LDP]
    unsigned short* ks = qs + 48 * LDP;

    const unsigned short* rowp = qkvT + (size_t)z * HW * CH3 +
                                 (size_t)(sl * 128 + (t >> 1)) * CH3;
    int half = t & 1, pl = t >> 1;
#pragma unroll
    for (int ci = 0; ci < 3; ++ci) {
        int cg = half * 3 + ci;
        u16x8 uq = *(const u16x8*)(rowp + hh * CHH + cg * 8);
        u16x8 uk = *(const u16x8*)(rowp + 192 + hh * CHH + cg * 8);
#pragma unroll
        for (int j = 0; j < 8; ++j) {
            qs[(cg * 8 + j) * LDP + pl] = uq[j];
            ks[(cg * 8 + j) * LDP + pl] = uk[j];
        }
    }
    __syncthreads();

    v4f acc[3][3];
#pragma unroll
    for (int mi = 0; mi < 3; ++mi)
#pragma unroll
        for (int ni = 0; ni < 3; ++ni) acc[mi][ni] = (v4f)0.0f;

    int kp = wid * 32;    // each wave one p-quarter
    v8s a[3], b[3];
#pragma unroll
    for (int i = 0; i < 3; ++i) {
        a[i] = *(const v8s*)&qs[(i * 16 + lm) * LDP + kp + quad * 8];
        b[i] = *(const v8s*)&ks[(i * 16 + lm) * LDP + kp + quad * 8];
    }
#pragma unroll
    for (int mi = 0; mi < 3; ++mi)
#pragma unroll
        for (int ni = 0; ni < 3; ++ni)
            acc[mi][ni] = __builtin_amdgcn_mfma_f32_16x16x32_bf16(a[mi], b[ni], acc[mi][ni], 0, 0, 0);

    __syncthreads();   // staged data consumed; safe to overwrite with Gs
#pragma unroll
    for (int mi = 0; mi < 3; ++mi)
#pragma unroll
        for (int ni = 0; ni < 3; ++ni)
#pragma unroll
            for (int r = 0; r < 4; ++r)
                Gs[wid][(mi * 16 + quad * 4 + r) * 48 + ni * 16 + lm] = acc[mi][ni][r];
    __syncthreads();
    float* gp = G0p + (((size_t)z * NHEADS + hh) * NSL2 + sl) * 2304;
    for (int i = t; i < 2304; i += 256)
        gp[i] = Gs[0][i] + Gs[1][i] + Gs[2][i] + Gs[3][i];
}

// ---------------------------------------------------------------------------
// softmax over d with inline inv-norms; outputs bf16 A zero-padded [48][64].
// grid (4, Z) x 256
// ---------------------------------------------------------------------------
__global__ __launch_bounds__(256) void softmax1(const float* __restrict__ G0p,
                                                const float* __restrict__ ssbuf,
                                                const float* __restrict__ temp,
                                                unsigned short* __restrict__ Apad) {
    int hh = blockIdx.x, z = blockIdx.y, t = threadIdx.x;
    __shared__ float Gsum[2304];
    const float* gb = G0p + ((size_t)z * NHEADS + hh) * NSL2 * 2304;
    for (int i = t; i < 2304; i += 256) {
        float s = 0.f;
#pragma unroll 8
        for (int sl = 0; sl < NSL2; ++sl) s += gb[(size_t)sl * 2304 + i];
        Gsum[i] = s;
    }
    __syncthreads();
    if (t < 48) {
        float T = temp[hh];
        const float* sb = ssbuf + z * 384;
        float invq = 1.0f / fmaxf(sqrtf(sb[hh * CHH + t]), 1e-12f);
        float lg[48];
        float mx = -1e30f;
#pragma unroll
        for (int d = 0; d < 48; ++d) {
            float invk = 1.0f / fmaxf(sqrtf(sb[192 + hh * CHH + d]), 1e-12f);
            float l = T * Gsum[t * 48 + d] * invq * invk;
            lg[d] = l;
            mx = fmaxf(mx, l);
        }
        float sum = 0.f;
#pragma unroll
        for (int d = 0; d < 48; ++d) { float e = expf(lg[d] - mx); lg[d] = e; sum += e; }
        float inv = 1.0f / sum;
        unsigned short* ap = Apad + ((size_t)z * NHEADS + hh) * 48 * 64 + t * 64;
#pragma unroll
        for (int d = 0; d < 48; ++d) ap[d] = f2bf(lg[d] * inv);
#pragma unroll
        for (int d = 48; d < 64; ++d) ap[d] = 0;
    }
}

// ---------------------------------------------------------------------------
// PV apply via MFMA: out[p][c] = sum_d V[p][d]*A[c][d]. V NHWC direct; A bf16
// padded [48][64] (zeros kill the K=48..63 overread). grid (64, 4, Z)
// ---------------------------------------------------------------------------
__global__ __launch_bounds__(256) void apply_pv(const unsigned short* __restrict__ qkvT,
                                                const unsigned short* __restrict__ Apad,
                                                unsigned short* __restrict__ attnout) {
    const int t = threadIdx.x;
    const int hh = blockIdx.y, z = blockIdx.z;
    const int wid = t >> 6, lane = t & 63, lm = lane & 15, quad = lane >> 4;
    const int p0 = blockIdx.x * 256 + wid * 64;

    const unsigned short* Vz = qkvT + (size_t)z * HW * CH3 + 384 + hh * CHH;
    const unsigned short* Ab = Apad + ((size_t)z * NHEADS + hh) * 48 * 64;

    v4f acc[4][3];
#pragma unroll
    for (int i = 0; i < 4; ++i)
#pragma unroll
        for (int j = 0; j < 3; ++j) acc[i][j] = (v4f)0.0f;

#pragma unroll
    for (int ks = 0; ks < 2; ++ks) {
        v8s a[4], b[3];
#pragma unroll
        for (int i = 0; i < 4; ++i)
            a[i] = *(const v8s*)(Vz + (size_t)(p0 + i * 16 + lm) * CH3 + ks * 32 + quad * 8);
#pragma unroll
        for (int j = 0; j < 3; ++j)
            b[j] = *(const v8s*)(Ab + (j * 16 + lm) * 64 + ks * 32 + quad * 8);
#pragma unroll
        for (int i = 0; i < 4; ++i)
#pragma unroll
            for (int j = 0; j < 3; ++j)
                acc[i][j] = __builtin_amdgcn_mfma_f32_16x16x32_bf16(a[i], b[j], acc[i][j], 0, 0, 0);
    }

    unsigned short* Oz = attnout + (size_t)z * HW * CDIM + hh * CHH;
#pragma unroll
    for (int i = 0; i < 4; ++i)
#pragma unroll
        for (int j = 0; j < 3; ++j)
#pragma unroll
            for (int r = 0; r < 4; ++r) {
                int p = p0 + i * 16 + quad * 4 + r;
                Oz[(size_t)p * CDIM + j * 16 + lm] = f2bf(acc[i][j][r]);
            }
}

// ---------------------------------------------------------------------------
// FFN grouped 3x3 (192->576) NHWC: 8 in-ch -> 24 out-ch per thread.
// grid (64, 24, Z)
// ---------------------------------------------------------------------------
__global__ __launch_bounds__(256) void dw1_nhwc(const unsigned short* __restrict__ xn,
                                                const unsigned short* __restrict__ wT,
                                                const float* __restrict__ b1,
                                                unsigned short* __restrict__ f1) {
    int t = threadIdx.x;
    int px = blockIdx.x * 256 + t;
    int g0 = blockIdx.y * 8, c0 = g0 * 3;
    int z = blockIdx.z;
    int h = px >> 7, w = px & 127;
    const unsigned short* ip = xn + (size_t)z * HW * CDIM;
    float acc[24];
#pragma unroll
    for (int j = 0; j < 24; ++j) acc[j] = b1[c0 + j];
#pragma unroll
    for (int ky = 0; ky < 3; ++ky) {
        int hy = h + ky - 1;
        if ((unsigned)hy >= 128u) continue;
#pragma unroll
        for (int kx = 0; kx < 3; ++kx) {
            int wx = w + kx - 1;
            if ((unsigned)wx >= 128u) continue;
            u16x8 xv = *(const u16x8*)(ip + (size_t)((hy << 7) + wx) * CDIM + g0);
            float mv[8];
#pragma unroll
            for (int j = 0; j < 8; ++j) mv[j] = bf2f(xv[j]);
            const unsigned short* wp = wT + (ky * 3 + kx) * CH3 + c0;
            u16x8 w0 = *(const u16x8*)wp;
            u16x8 w1 = *(const u16x8*)(wp + 8);
            u16x8 w2 = *(const u16x8*)(wp + 16);
            float wv[24];
#pragma unroll
            for (int j = 0; j < 8; ++j) {
                wv[j] = bf2f(w0[j]); wv[8 + j] = bf2f(w1[j]); wv[16 + j] = bf2f(w2[j]);
            }
#pragma unroll
            for (int j = 0; j < 24; ++j) acc[j] = fmaf(wv[j], mv[j / 3], acc[j]);
        }
    }
    unsigned short* op = f1 + (size_t)z * HW * CH3 + (size_t)px * CH3 + c0;
#pragma unroll
    for (int q8 = 0; q8 < 3; ++q8) {
        u16x8 o;
#pragma unroll
        for (int j = 0; j < 8; ++j) o[j] = f2bf(acc[q8 * 8 + j]);
        *(u16x8*)(op + q8 * 8) = o;
    }
}

// ---------------------------------------------------------------------------
// Depthwise 3x3 NHWC 576ch (FFN dw2). grid (64, 72, Z)
// ---------------------------------------------------------------------------
__global__ __launch_bounds__(256) void dw2_nhwc(const unsigned short* __restrict__ in,
                                                const unsigned short* __restrict__ wT,
                                                const float* __restrict__ b1,
                                                unsigned short* __restrict__ out) {
    int t = threadIdx.x;
    int px = blockIdx.x * 256 + t;
    int c0 = blockIdx.y * 8;
    int z = blockIdx.z;
    int h = px >> 7, w = px & 127;
    const unsigned short* ip = in + (size_t)z * HW * CH3;
    float acc[8];
#pragma unroll
    for (int j = 0; j < 8; ++j) acc[j] = b1[c0 + j];
#pragma unroll
    for (int ky = 0; ky < 3; ++ky) {
        int hy = h + ky - 1;
        if ((unsigned)hy >= 128u) continue;
#pragma unroll
        for (int kx = 0; kx < 3; ++kx) {
            int wx = w + kx - 1;
            if ((unsigned)wx >= 128u) continue;
            u16x8 xv = *(const u16x8*)(ip + (size_t)((hy << 7) + wx) * CH3 + c0);
            u16x8 wv = *(const u16x8*)(wT + (ky * 3 + kx) * CH3 + c0);
#pragma unroll
            for (int j = 0; j < 8; ++j) acc[j] = fmaf(bf2f(wv[j]), bf2f(xv[j]), acc[j]);
        }
    }
    u16x8 o;
#pragma unroll
    for (int j = 0; j < 8; ++j) o[j] = f2bf(acc[j]);
    *(u16x8*)(out + (size_t)z * HW * CH3 + (size_t)px * CH3 + c0) = o;
}

// ---------------------------------------------------------------------------
extern "C" void kernel_launch(void* const* d_in, const int* in_sizes, int n_in,
                              void* d_out, int out_size, void* d_ws, size_t ws_size,
                              hipStream_t stream) {
    const float* x      = (const float*)d_in[0];
    const float* ln1w   = (const float*)d_in[1];
    const float* ln1b   = (const float*)d_in[2];
    const float* qkv_w  = (const float*)d_in[3];
    const float* qkv_b  = (const float*)d_in[4];
    const float* qdw_w  = (const float*)d_in[5];
    const float* qdw_b  = (const float*)d_in[6];
    const float* temp   = (const float*)d_in[7];
    const float* prompt = (const float*)d_in[8];
    const float* proj_w = (const float*)d_in[9];
    const float* proj_b = (const float*)d_in[10];
    const float* ln2w   = (const float*)d_in[11];
    const float* ln2b   = (const float*)d_in[12];
    const float* dw1_w  = (const float*)d_in[13];
    const float* dw1_b  = (const float*)d_in[14];
    const float* pm_w   = (const float*)d_in[15];
    const float* pm_b   = (const float*)d_in[16];
    const float* dw2_w  = (const float*)d_in[17];
    const float* dw2_b  = (const float*)d_in[18];
    const float* po_w   = (const float*)d_in[19];
    const float* po_b   = (const float*)d_in[20];
    float* out = (float*)d_out;
    (void)in_sizes; (void)n_in; (void)out_size;

    const int NWQ = CH3 * CDIM, NWP = CDIM * CDIM, NWM = CH3 * CH3, NWO = CDIM * CH3;
    const int NWALL = NWQ + NWP + NWM + NWO;

    auto al = [](size_t b) { return (b + 255) & ~(size_t)255; };
    auto need = [&](int PG) -> size_t {
        return 2 * al((size_t)PG * HW * CH3 * 2)              // regionA, regionB
             + al((size_t)PG * HW * CDIM * 2)                  // xn / G0p union
             + al((size_t)PG * NHEADS * 48 * 64 * 2)           // Apad
             + al((size_t)PG * 384 * 4)                        // ssbuf
             + al((size_t)(NWALL + 3 * 9 * CH3) * 2) + 4096;
    };
    int PG = 8;
    while (PG > 1 && need(PG) > ws_size) PG >>= 1;

    size_t off = 0;
    char* base = (char*)d_ws;
    auto alloc = [&](size_t bytes) -> char* {
        char* p = base + off;
        off = (off + bytes + 255) & ~(size_t)255;
        return p;
    };
    unsigned short* regionA = (unsigned short*)alloc((size_t)PG * HW * CH3 * 2);
    unsigned short* regionB = (unsigned short*)alloc((size_t)PG * HW * CH3 * 2);
    unsigned short* xng     = (unsigned short*)alloc((size_t)PG * HW * CDIM * 2);
    unsigned short* Apad    = (unsigned short*)alloc((size_t)PG * NHEADS * 48 * 64 * 2);
    float*          ssbuf   = (float*)alloc((size_t)PG * 384 * 4);
    unsigned short* wbf     = (unsigned short*)alloc((size_t)(NWALL + 3 * 9 * CH3) * 2);

    unsigned short* wq   = wbf;
    unsigned short* wpj  = wbf + NWQ;
    unsigned short* wpm  = wbf + NWQ + NWP;
    unsigned short* wpo  = wbf + NWQ + NWP + NWM;
    unsigned short* wdwT = wbf + NWALL;
    unsigned short* wd1T = wdwT + 9 * CH3;
    unsigned short* wd2T = wd1T + 9 * CH3;

    unsigned short* preQKV  = regionA;   // attn: [z][p][576]
    unsigned short* attnout = regionA;   // [z][p][192] (preQKV dead)
    unsigned short* f1      = regionA;   // ffn
    unsigned short* f3      = regionA;   // aliases f1 (dead after pm)
    unsigned short* qkvT    = regionB;
    unsigned short* f2      = regionB;
    float* G0p = (float*)xng;            // aliases xn (dead after qkv GEMM)

    dim3 blk(256);

    wcvt<<<dim3(162, 7), blk, 0, stream>>>(qkv_w, proj_w, pm_w, po_w,
                                           qdw_w, dw1_w, dw2_w,
                                           wbf, NWQ, NWP, NWM, NWO);

    for (int b0 = 0; b0 < NB; b0 += PG) {
        const float* xb = x + (size_t)b0 * CDIM * HW;
        float* x2b      = out + (size_t)b0 * CDIM * HW;

        // ---------- attention ----------
        zero_f<<<dim3((PG * 384 + 255) / 256), blk, 0, stream>>>(ssbuf, PG * 384);
        ln_norm<<<dim3(64, PG), blk, 0, stream>>>(xb, ln1w, ln1b, xng);
        gemm_nhwc<0, CDIM><<<dim3(128, 6, PG), blk, 0, stream>>>(
            wq, xng, qkv_b, preQKV, CH3);
        dwp_nhwc<<<dim3(64, 72, PG), blk, 0, stream>>>(
            preQKV, wdwT, qdw_b, prompt, qkvT, ssbuf);
        gram1<<<dim3(NSL2, NHEADS, PG), blk, 0, stream>>>(qkvT, G0p);
        softmax1<<<dim3(NHEADS, PG), blk, 0, stream>>>(G0p, ssbuf, temp, Apad);
        apply_pv<<<dim3(64, NHEADS, PG), blk, 0, stream>>>(qkvT, Apad, attnout);
        gemm_nchw<CDIM><<<dim3(128, 3, PG), blk, 0, stream>>>(
            wpj, attnout, proj_b, xb, x2b);

        // ---------- FFN ----------
        ln_norm<<<dim3(64, PG), blk, 0, stream>>>(x2b, ln2w, ln2b, xng);
        dw1_nhwc<<<dim3(64, 24, PG), blk, 0, stream>>>(xng, wd1T, dw1_b, f1);
        gemm_nhwc<1, CH3><<<dim3(128, 6, PG), blk, 0, stream>>>(
            wpm, f1, pm_b, f2, CH3);
        dw2_nhwc<<<dim3(64, 72, PG), blk, 0, stream>>>(f2, wd2T, dw2_b, f3);
        gemm_nchw<CH3><<<dim3(128, 3, PG), blk, 0, stream>>>(
            wpo, f3, po_b, x2b, x2b);
    }
}

// Round 7
// 1806.653 us; speedup vs baseline: 1.0982x; 1.0982x over previous
//
#include <hip/hip_runtime.h>

// Problem constants
#define HW     16384      // 128*128
#define NB     8
#define CDIM   192
#define CH3    576
#define NHEADS 4
#define CHH    48
#define NSL2   128        // gram pixel-slices (128 px each)
#define LDP    136        // gram LDS row stride
#define KT     64         // GEMM K-tile
#define LDK    72         // GEMM LDS row stride (36 dwords: banks at floor)

typedef short  v8s  __attribute__((ext_vector_type(8)));
typedef float  v4f  __attribute__((ext_vector_type(4)));
typedef unsigned short u16x8 __attribute__((ext_vector_type(8)));

__device__ __forceinline__ float bf2f(unsigned short s) {
    return __uint_as_float(((unsigned)s) << 16);
}
__device__ __forceinline__ unsigned short f2bf(float f) {
    unsigned u = __float_as_uint(f);
    return (unsigned short)((u + 0x7fffu + ((u >> 16) & 1u)) >> 16);
}
__device__ __forceinline__ float gelu_f(float x) {
    return 0.5f * x * (1.0f + erff(x * 0.70710678118654752f));
}

// ---------------------------------------------------------------------------
// Weight prep: 4 GEMM mats fp32->bf16 packed; 3 depthwise mats transposed to
// [tap][576] bf16. grid (162, 7)
// ---------------------------------------------------------------------------
__global__ __launch_bounds__(256) void wcvt(const float* __restrict__ s0,
                                            const float* __restrict__ s1,
                                            const float* __restrict__ s2,
                                            const float* __restrict__ s3,
                                            const float* __restrict__ dq,
                                            const float* __restrict__ d1,
                                            const float* __restrict__ d2,
                                            unsigned short* __restrict__ d,
                                            int n0, int n1, int n2, int n3) {
    int y = blockIdx.y;
    if (y < 4) {
        const float* srcs[4] = {s0, s1, s2, s3};
        int cnts[4] = {n0, n1, n2, n3};
        int offs[4] = {0, n0, n0 + n1, n0 + n1 + n2};
        const float* s = srcs[y];
        unsigned short* o = d + offs[y];
        int i = (blockIdx.x * 256 + threadIdx.x) * 8;
        if (i + 8 <= cnts[y]) {
            float4 a = *(const float4*)(s + i);
            float4 b = *(const float4*)(s + i + 4);
            u16x8 u;
            u[0] = f2bf(a.x); u[1] = f2bf(a.y); u[2] = f2bf(a.z); u[3] = f2bf(a.w);
            u[4] = f2bf(b.x); u[5] = f2bf(b.y); u[6] = f2bf(b.z); u[7] = f2bf(b.w);
            *(u16x8*)(o + i) = u;
        }
    } else {
        const float* s = (y == 4) ? dq : (y == 5) ? d1 : d2;
        unsigned short* o = d + (n0 + n1 + n2 + n3) + (y - 4) * 9 * CH3;
        int i = blockIdx.x * 256 + threadIdx.x;
        if (i < 9 * CH3) {
            int tap = i / CH3, c = i - tap * CH3;
            o[i] = f2bf(s[c * 9 + tap]);
        }
    }
}

__global__ __launch_bounds__(256) void zero_f(float* __restrict__ p, int n) {
    int i = blockIdx.x * 256 + threadIdx.x;
    if (i < n) p[i] = 0.f;
}

// ---------------------------------------------------------------------------
// LayerNorm: NCHW fp32 in -> NHWC bf16 out. grid (64, Z)
// ---------------------------------------------------------------------------
__global__ __launch_bounds__(256) void ln_norm(const float* __restrict__ x,
                                               const float* __restrict__ lnw,
                                               const float* __restrict__ lnb,
                                               unsigned short* __restrict__ xn) {
    int p = blockIdx.x * 256 + threadIdx.x;
    int z = blockIdx.y;
    const float* xp = x + (size_t)z * CDIM * HW;
    float s = 0.f, ss = 0.f;
    for (int c = 0; c < CDIM; ++c) {
        float v = xp[(size_t)c * HW + p];
        s += v; ss += v * v;
    }
    float m = s * (1.0f / CDIM);
    float var = ss * (1.0f / CDIM) - m * m;
    float r = 1.0f / sqrtf(var + 1e-5f);
    unsigned short* op = xn + ((size_t)z * HW + p) * CDIM;
    for (int c8 = 0; c8 < CDIM; c8 += 8) {
        u16x8 u;
#pragma unroll
        for (int j = 0; j < 8; ++j)
            u[j] = f2bf((xp[(size_t)(c8 + j) * HW + p] - m) * r * lnw[c8 + j] + lnb[c8 + j]);
        *(u16x8*)(op + c8) = u;
    }
}

// ---------------------------------------------------------------------------
// NHWC GEMM, LDS-staged X: out[p][ch] = sum_k X[p][k]*W[ch][k], bf16 out.
// Block 128px x 192ch, 4 waves (2px x 2ch), wave 64px x 96ch.
// X tile [128][KT] in LDS (LDK=72 -> banks at transfer floor both sides);
// each thread stages 32 elems via 4x u16x8; next tile's loads issued before
// the barrier (hide under current tile's 48 MFMAs). W direct global (L2-hot).
// EPI 0: +bias; 1: +bias+gelu. grid (128, M/192, Z)
// ---------------------------------------------------------------------------
template <int EPI, int K>
__global__ __launch_bounds__(256) void gemm_nhwc(
    const unsigned short* __restrict__ Wb,
    const unsigned short* __restrict__ X,
    const float* __restrict__ bias,
    unsigned short* __restrict__ out, int MS) {
    __shared__ unsigned short Xs[128 * LDK];
    const int t = threadIdx.x;
    const int p0 = blockIdx.x * 128, M0 = blockIdx.y * 192, z = blockIdx.z;
    const int wid = t >> 6, lane = t & 63, lm = lane & 15, quad = lane >> 4;
    const int wp = (wid & 1) * 64, wc = (wid >> 1) * 96;

    const unsigned short* Xz = X + (size_t)z * HW * K;
    // staging: thread covers row t>>1, elems (t&1)*32 .. +31 (4x u16x8)
    const int srow = t >> 1, shalf = (t & 1) * 32;
    const unsigned short* sp = Xz + (size_t)(p0 + srow) * K + shalf;
    unsigned short* sd = &Xs[srow * LDK + shalf];

    v4f acc[4][6];
#pragma unroll
    for (int i = 0; i < 4; ++i)
#pragma unroll
        for (int j = 0; j < 6; ++j) acc[i][j] = (v4f)0.0f;

    const unsigned short* br[6];
#pragma unroll
    for (int j = 0; j < 6; ++j)
        br[j] = Wb + (size_t)(M0 + wc + j * 16 + lm) * K + quad * 8;

    for (int kt = 0; kt < K; kt += KT) {
        u16x8 g0 = *(const u16x8*)(sp + kt);
        u16x8 g1 = *(const u16x8*)(sp + kt + 8);
        u16x8 g2 = *(const u16x8*)(sp + kt + 16);
        u16x8 g3 = *(const u16x8*)(sp + kt + 24);
        if (kt) __syncthreads();
        *(u16x8*)sd = g0;
        *(u16x8*)(sd + 8) = g1;
        *(u16x8*)(sd + 16) = g2;
        *(u16x8*)(sd + 24) = g3;
        __syncthreads();
#pragma unroll
        for (int ks = 0; ks < 2; ++ks) {
            v8s a[4], b[6];
#pragma unroll
            for (int i = 0; i < 4; ++i)
                a[i] = *(const v8s*)&Xs[(wp + i * 16 + lm) * LDK + ks * 32 + quad * 8];
#pragma unroll
            for (int j = 0; j < 6; ++j)
                b[j] = *(const v8s*)(br[j] + kt + ks * 32);
#pragma unroll
            for (int i = 0; i < 4; ++i)
#pragma unroll
                for (int j = 0; j < 6; ++j)
                    acc[i][j] = __builtin_amdgcn_mfma_f32_16x16x32_bf16(a[i], b[j], acc[i][j], 0, 0, 0);
        }
    }

    unsigned short* Oz = out + (size_t)z * HW * MS;
#pragma unroll
    for (int i = 0; i < 4; ++i)
#pragma unroll
        for (int j = 0; j < 6; ++j) {
            int ch = M0 + wc + j * 16 + lm;
            float bch = bias[ch];
#pragma unroll
            for (int r = 0; r < 4; ++r) {
                int p = p0 + wp + i * 16 + quad * 4 + r;
                float v = acc[i][j][r] + bch;
                if (EPI == 1) v = gelu_f(v);
                Oz[(size_t)p * MS + ch] = f2bf(v);
            }
        }
}

// ---------------------------------------------------------------------------
// NCHW-output GEMM, LDS-staged X: out[m][p] = sum_k W[m][k]*X[p][k] + res,
// fp32 NCHW. Block 192ch x 128px (all M), 4 waves (2ch x 2px), wave 96x64.
// grid (128, 1, Z)
// ---------------------------------------------------------------------------
template <int K>
__global__ __launch_bounds__(256) void gemm_nchw(
    const unsigned short* __restrict__ Wb,
    const unsigned short* __restrict__ X,
    const float* __restrict__ bias,
    const float* __restrict__ res,
    float* __restrict__ outp) {
    __shared__ unsigned short Xs[128 * LDK];
    const int t = threadIdx.x;
    const int p0 = blockIdx.x * 128, z = blockIdx.z;
    const int wid = t >> 6, lane = t & 63, lm = lane & 15, quad = lane >> 4;
    const int wm = (wid >> 1) * 96, wph = (wid & 1) * 64;

    const unsigned short* Xz = X + (size_t)z * HW * K;
    const int srow = t >> 1, shalf = (t & 1) * 32;
    const unsigned short* sp = Xz + (size_t)(p0 + srow) * K + shalf;
    unsigned short* sd = &Xs[srow * LDK + shalf];

    v4f acc[6][4];
#pragma unroll
    for (int i = 0; i < 6; ++i)
#pragma unroll
        for (int j = 0; j < 4; ++j) acc[i][j] = (v4f)0.0f;

    const unsigned short* ar[6];
#pragma unroll
    for (int i = 0; i < 6; ++i)
        ar[i] = Wb + (size_t)(wm + i * 16 + lm) * K + quad * 8;

    for (int kt = 0; kt < K; kt += KT) {
        u16x8 g0 = *(const u16x8*)(sp + kt);
        u16x8 g1 = *(const u16x8*)(sp + kt + 8);
        u16x8 g2 = *(const u16x8*)(sp + kt + 16);
        u16x8 g3 = *(const u16x8*)(sp + kt + 24);
        if (kt) __syncthreads();
        *(u16x8*)sd = g0;
        *(u16x8*)(sd + 8) = g1;
        *(u16x8*)(sd + 16) = g2;
        *(u16x8*)(sd + 24) = g3;
        __syncthreads();
#pragma unroll
        for (int ks = 0; ks < 2; ++ks) {
            v8s a[6], b[4];
#pragma unroll
            for (int i = 0; i < 6; ++i)
                a[i] = *(const v8s*)(ar[i] + kt + ks * 32);
#pragma unroll
            for (int j = 0; j < 4; ++j)
                b[j] = *(const v8s*)&Xs[(wph + j * 16 + lm) * LDK + ks * 32 + quad * 8];
#pragma unroll
            for (int i = 0; i < 6; ++i)
#pragma unroll
                for (int j = 0; j < 4; ++j)
                    acc[i][j] = __builtin_amdgcn_mfma_f32_16x16x32_bf16(a[i], b[j], acc[i][j], 0, 0, 0);
        }
    }

#pragma unroll
    for (int i = 0; i < 6; ++i)
#pragma unroll
        for (int j = 0; j < 4; ++j) {
            int gp = p0 + wph + j * 16 + lm;
#pragma unroll
            for (int r = 0; r < 4; ++r) {
                int gm = wm + i * 16 + quad * 4 + r;
                size_t oi = (size_t)z * CDIM * HW + (size_t)gm * HW + gp;
                outp[oi] = acc[i][j][r] + bias[gm] + res[oi];
            }
        }
}

// ---------------------------------------------------------------------------
// Depthwise 3x3 + bias + prompt on NHWC 576ch, 8 ch/thread, fused sum-sq
// atomics for q,k channels. grid (64, 72, Z)
// ---------------------------------------------------------------------------
__global__ __launch_bounds__(256) void dwp_nhwc(const unsigned short* __restrict__ in,
                                                const unsigned short* __restrict__ wT,
                                                const float* __restrict__ b1,
                                                const float* __restrict__ prompt,
                                                unsigned short* __restrict__ out,
                                                float* __restrict__ ssbuf) {
    int t = threadIdx.x;
    int px = blockIdx.x * 256 + t;
    int c0 = blockIdx.y * 8;
    int z = blockIdx.z;
    int h = px >> 7, w = px & 127;
    const unsigned short* ip = in + (size_t)z * HW * CH3;
    int pc = c0 % CDIM;
    float acc[8];
#pragma unroll
    for (int j = 0; j < 8; ++j) acc[j] = b1[c0 + j] + prompt[pc + j];
#pragma unroll
    for (int ky = 0; ky < 3; ++ky) {
        int hy = h + ky - 1;
        if ((unsigned)hy >= 128u) continue;
#pragma unroll
        for (int kx = 0; kx < 3; ++kx) {
            int wx = w + kx - 1;
            if ((unsigned)wx >= 128u) continue;
            u16x8 xv = *(const u16x8*)(ip + (size_t)((hy << 7) + wx) * CH3 + c0);
            u16x8 wv = *(const u16x8*)(wT + (ky * 3 + kx) * CH3 + c0);
#pragma unroll
            for (int j = 0; j < 8; ++j) acc[j] = fmaf(bf2f(wv[j]), bf2f(xv[j]), acc[j]);
        }
    }
    u16x8 o;
    float sl[8];
#pragma unroll
    for (int j = 0; j < 8; ++j) {
        unsigned short q = f2bf(acc[j]);
        o[j] = q;
        float vr = bf2f(q);
        sl[j] = vr * vr;
    }
    *(u16x8*)(out + (size_t)z * HW * CH3 + (size_t)px * CH3 + c0) = o;

    if (c0 < 384) {   // q,k channels: accumulate sum-squares
        int wid = t >> 6, lane = t & 63;
#pragma unroll
        for (int j = 0; j < 8; ++j)
            for (int off = 32; off; off >>= 1) sl[j] += __shfl_down(sl[j], off);
        __shared__ float wr[4][8];
        if (lane == 0)
#pragma unroll
            for (int j = 0; j < 8; ++j) wr[wid][j] = sl[j];
        __syncthreads();
        if (t < 8) {
            float s = wr[0][t] + wr[1][t] + wr[2][t] + wr[3][t];
            atomicAdd(&ssbuf[z * 384 + c0 + t], s);
        }
    }
}

// ---------------------------------------------------------------------------
// Gram partials: G[cq][ck] = sum_p q[p][cq]*k[p][ck] per 128-px slice.
// LDS transpose-stage NHWC -> [c][p], then MFMA (waves split p). grid (128,4,Z)
// ---------------------------------------------------------------------------
__global__ __launch_bounds__(256) void gram1(const unsigned short* __restrict__ qkvT,
                                             float* __restrict__ G0p) {
    const int sl = blockIdx.x, hh = blockIdx.y, z = blockIdx.z;
    const int t = threadIdx.x;
    const int wid = t >> 6, lane = t & 63, lm = lane & 15, quad = lane >> 4;

    __shared__ float Gs[4][2304];                       // 36.9 KB, aliased below
    unsigned short* qs = (unsigned short*)&Gs[0][0];    // [48][LDP]
    unsigned short* ks = qs + 48 * LDP;

    const unsigned short* rowp = qkvT + (size_t)z * HW * CH3 +
                                 (size_t)(sl * 128 + (t >> 1)) * CH3;
    int half = t & 1, pl = t >> 1;
#pragma unroll
    for (int ci = 0; ci < 3; ++ci) {
        int cg = half * 3 + ci;
        u16x8 uq = *(const u16x8*)(rowp + hh * CHH + cg * 8);
        u16x8 uk = *(const u16x8*)(rowp + 192 + hh * CHH + cg * 8);
#pragma unroll
        for (int j = 0; j < 8; ++j) {
            qs[(cg * 8 + j) * LDP + pl] = uq[j];
            ks[(cg * 8 + j) * LDP + pl] = uk[j];
        }
    }
    __syncthreads();

    v4f acc[3][3];
#pragma unroll
    for (int mi = 0; mi < 3; ++mi)
#pragma unroll
        for (int ni = 0; ni < 3; ++ni) acc[mi][ni] = (v4f)0.0f;

    int kp = wid * 32;    // each wave one p-quarter
    v8s a[3], b[3];
#pragma unroll
    for (int i = 0; i < 3; ++i) {
        a[i] = *(const v8s*)&qs[(i * 16 + lm) * LDP + kp + quad * 8];
        b[i] = *(const v8s*)&ks[(i * 16 + lm) * LDP + kp + quad * 8];
    }
#pragma unroll
    for (int mi = 0; mi < 3; ++mi)
#pragma unroll
        for (int ni = 0; ni < 3; ++ni)
            acc[mi][ni] = __builtin_amdgcn_mfma_f32_16x16x32_bf16(a[mi], b[ni], acc[mi][ni], 0, 0, 0);

    __syncthreads();   // staged data consumed; safe to overwrite with Gs
#pragma unroll
    for (int mi = 0; mi < 3; ++mi)
#pragma unroll
        for (int ni = 0; ni < 3; ++ni)
#pragma unroll
            for (int r = 0; r < 4; ++r)
                Gs[wid][(mi * 16 + quad * 4 + r) * 48 + ni * 16 + lm] = acc[mi][ni][r];
    __syncthreads();
    float* gp = G0p + (((size_t)z * NHEADS + hh) * NSL2 + sl) * 2304;
    for (int i = t; i < 2304; i += 256)
        gp[i] = Gs[0][i] + Gs[1][i] + Gs[2][i] + Gs[3][i];
}

// ---------------------------------------------------------------------------
// softmax over d with inline inv-norms; outputs bf16 A zero-padded [48][64].
// grid (4, Z) x 256
// ---------------------------------------------------------------------------
__global__ __launch_bounds__(256) void softmax1(const float* __restrict__ G0p,
                                                const float* __restrict__ ssbuf,
                                                const float* __restrict__ temp,
                                                unsigned short* __restrict__ Apad) {
    int hh = blockIdx.x, z = blockIdx.y, t = threadIdx.x;
    __shared__ float Gsum[2304];
    const float* gb = G0p + ((size_t)z * NHEADS + hh) * NSL2 * 2304;
    for (int i = t; i < 2304; i += 256) {
        float s = 0.f;
#pragma unroll 8
        for (int sl = 0; sl < NSL2; ++sl) s += gb[(size_t)sl * 2304 + i];
        Gsum[i] = s;
    }
    __syncthreads();
    if (t < 48) {
        float T = temp[hh];
        const float* sb = ssbuf + z * 384;
        float invq = 1.0f / fmaxf(sqrtf(sb[hh * CHH + t]), 1e-12f);
        float lg[48];
        float mx = -1e30f;
#pragma unroll
        for (int d = 0; d < 48; ++d) {
            float invk = 1.0f / fmaxf(sqrtf(sb[192 + hh * CHH + d]), 1e-12f);
            float l = T * Gsum[t * 48 + d] * invq * invk;
            lg[d] = l;
            mx = fmaxf(mx, l);
        }
        float sum = 0.f;
#pragma unroll
        for (int d = 0; d < 48; ++d) { float e = expf(lg[d] - mx); lg[d] = e; sum += e; }
        float inv = 1.0f / sum;
        unsigned short* ap = Apad + ((size_t)z * NHEADS + hh) * 48 * 64 + t * 64;
#pragma unroll
        for (int d = 0; d < 48; ++d) ap[d] = f2bf(lg[d] * inv);
#pragma unroll
        for (int d = 48; d < 64; ++d) ap[d] = 0;
    }
}

// ---------------------------------------------------------------------------
// PV apply via MFMA: out[p][c] = sum_d V[p][d]*A[c][d]. V NHWC direct; A bf16
// padded [48][64] (zeros kill the K=48..63 overread). grid (64, 4, Z)
// ---------------------------------------------------------------------------
__global__ __launch_bounds__(256) void apply_pv(const unsigned short* __restrict__ qkvT,
                                                const unsigned short* __restrict__ Apad,
                                                unsigned short* __restrict__ attnout) {
    const int t = threadIdx.x;
    const int hh = blockIdx.y, z = blockIdx.z;
    const int wid = t >> 6, lane = t & 63, lm = lane & 15, quad = lane >> 4;
    const int p0 = blockIdx.x * 256 + wid * 64;

    const unsigned short* Vz = qkvT + (size_t)z * HW * CH3 + 384 + hh * CHH;
    const unsigned short* Ab = Apad + ((size_t)z * NHEADS + hh) * 48 * 64;

    v4f acc[4][3];
#pragma unroll
    for (int i = 0; i < 4; ++i)
#pragma unroll
        for (int j = 0; j < 3; ++j) acc[i][j] = (v4f)0.0f;

#pragma unroll
    for (int ks = 0; ks < 2; ++ks) {
        v8s a[4], b[3];
#pragma unroll
        for (int i = 0; i < 4; ++i)
            a[i] = *(const v8s*)(Vz + (size_t)(p0 + i * 16 + lm) * CH3 + ks * 32 + quad * 8);
#pragma unroll
        for (int j = 0; j < 3; ++j)
            b[j] = *(const v8s*)(Ab + (j * 16 + lm) * 64 + ks * 32 + quad * 8);
#pragma unroll
        for (int i = 0; i < 4; ++i)
#pragma unroll
            for (int j = 0; j < 3; ++j)
                acc[i][j] = __builtin_amdgcn_mfma_f32_16x16x32_bf16(a[i], b[j], acc[i][j], 0, 0, 0);
    }

    unsigned short* Oz = attnout + (size_t)z * HW * CDIM + hh * CHH;
#pragma unroll
    for (int i = 0; i < 4; ++i)
#pragma unroll
        for (int j = 0; j < 3; ++j)
#pragma unroll
            for (int r = 0; r < 4; ++r) {
                int p = p0 + i * 16 + quad * 4 + r;
                Oz[(size_t)p * CDIM + j * 16 + lm] = f2bf(acc[i][j][r]);
            }
}

// ---------------------------------------------------------------------------
// FFN grouped 3x3 (192->576) NHWC: 8 in-ch -> 24 out-ch per thread.
// grid (64, 24, Z)
// ---------------------------------------------------------------------------
__global__ __launch_bounds__(256) void dw1_nhwc(const unsigned short* __restrict__ xn,
                                                const unsigned short* __restrict__ wT,
                                                const float* __restrict__ b1,
                                                unsigned short* __restrict__ f1) {
    int t = threadIdx.x;
    int px = blockIdx.x * 256 + t;
    int g0 = blockIdx.y * 8, c0 = g0 * 3;
    int z = blockIdx.z;
    int h = px >> 7, w = px & 127;
    const unsigned short* ip = xn + (size_t)z * HW * CDIM;
    float acc[24];
#pragma unroll
    for (int j = 0; j < 24; ++j) acc[j] = b1[c0 + j];
#pragma unroll
    for (int ky = 0; ky < 3; ++ky) {
        int hy = h + ky - 1;
        if ((unsigned)hy >= 128u) continue;
#pragma unroll
        for (int kx = 0; kx < 3; ++kx) {
            int wx = w + kx - 1;
            if ((unsigned)wx >= 128u) continue;
            u16x8 xv = *(const u16x8*)(ip + (size_t)((hy << 7) + wx) * CDIM + g0);
            float mv[8];
#pragma unroll
            for (int j = 0; j < 8; ++j) mv[j] = bf2f(xv[j]);
            const unsigned short* wp = wT + (ky * 3 + kx) * CH3 + c0;
            u16x8 w0 = *(const u16x8*)wp;
            u16x8 w1 = *(const u16x8*)(wp + 8);
            u16x8 w2 = *(const u16x8*)(wp + 16);
            float wv[24];
#pragma unroll
            for (int j = 0; j < 8; ++j) {
                wv[j] = bf2f(w0[j]); wv[8 + j] = bf2f(w1[j]); wv[16 + j] = bf2f(w2[j]);
            }
#pragma unroll
            for (int j = 0; j < 24; ++j) acc[j] = fmaf(wv[j], mv[j / 3], acc[j]);
        }
    }
    unsigned short* op = f1 + (size_t)z * HW * CH3 + (size_t)px * CH3 + c0;
#pragma unroll
    for (int q8 = 0; q8 < 3; ++q8) {
        u16x8 o;
#pragma unroll
        for (int j = 0; j < 8; ++j) o[j] = f2bf(acc[q8 * 8 + j]);
        *(u16x8*)(op + q8 * 8) = o;
    }
}

// ---------------------------------------------------------------------------
// Depthwise 3x3 NHWC 576ch (FFN dw2). grid (64, 72, Z)
// ---------------------------------------------------------------------------
__global__ __launch_bounds__(256) void dw2_nhwc(const unsigned short* __restrict__ in,
                                                const unsigned short* __restrict__ wT,
                                                const float* __restrict__ b1,
                                                unsigned short* __restrict__ out) {
    int t = threadIdx.x;
    int px = blockIdx.x * 256 + t;
    int c0 = blockIdx.y * 8;
    int z = blockIdx.z;
    int h = px >> 7, w = px & 127;
    const unsigned short* ip = in + (size_t)z * HW * CH3;
    float acc[8];
#pragma unroll
    for (int j = 0; j < 8; ++j) acc[j] = b1[c0 + j];
#pragma unroll
    for (int ky = 0; ky < 3; ++ky) {
        int hy = h + ky - 1;
        if ((unsigned)hy >= 128u) continue;
#pragma unroll
        for (int kx = 0; kx < 3; ++kx) {
            int wx = w + kx - 1;
            if ((unsigned)wx >= 128u) continue;
            u16x8 xv = *(const u16x8*)(ip + (size_t)((hy << 7) + wx) * CH3 + c0);
            u16x8 wv = *(const u16x8*)(wT + (ky * 3 + kx) * CH3 + c0);
#pragma unroll
            for (int j = 0; j < 8; ++j) acc[j] = fmaf(bf2f(wv[j]), bf2f(xv[j]), acc[j]);
        }
    }
    u16x8 o;
#pragma unroll
    for (int j = 0; j < 8; ++j) o[j] = f2bf(acc[j]);
    *(u16x8*)(out + (size_t)z * HW * CH3 + (size_t)px * CH3 + c0) = o;
}

// ---------------------------------------------------------------------------
extern "C" void kernel_launch(void* const* d_in, const int* in_sizes, int n_in,
                              void* d_out, int out_size, void* d_ws, size_t ws_size,
                              hipStream_t stream) {
    const float* x      = (const float*)d_in[0];
    const float* ln1w   = (const float*)d_in[1];
    const float* ln1b   = (const float*)d_in[2];
    const float* qkv_w  = (const float*)d_in[3];
    const float* qkv_b  = (const float*)d_in[4];
    const float* qdw_w  = (const float*)d_in[5];
    const float* qdw_b  = (const float*)d_in[6];
    const float* temp   = (const float*)d_in[7];
    const float* prompt = (const float*)d_in[8];
    const float* proj_w = (const float*)d_in[9];
    const float* proj_b = (const float*)d_in[10];
    const float* ln2w   = (const float*)d_in[11];
    const float* ln2b   = (const float*)d_in[12];
    const float* dw1_w  = (const float*)d_in[13];
    const float* dw1_b  = (const float*)d_in[14];
    const float* pm_w   = (const float*)d_in[15];
    const float* pm_b   = (const float*)d_in[16];
    const float* dw2_w  = (const float*)d_in[17];
    const float* dw2_b  = (const float*)d_in[18];
    const float* po_w   = (const float*)d_in[19];
    const float* po_b   = (const float*)d_in[20];
    float* out = (float*)d_out;
    (void)in_sizes; (void)n_in; (void)out_size;

    const int NWQ = CH3 * CDIM, NWP = CDIM * CDIM, NWM = CH3 * CH3, NWO = CDIM * CH3;
    const int NWALL = NWQ + NWP + NWM + NWO;

    auto al = [](size_t b) { return (b + 255) & ~(size_t)255; };
    auto need = [&](int PG) -> size_t {
        return 2 * al((size_t)PG * HW * CH3 * 2)              // regionA, regionB
             + al((size_t)PG * HW * CDIM * 2)                  // xn / G0p union
             + al((size_t)PG * NHEADS * 48 * 64 * 2)           // Apad
             + al((size_t)PG * 384 * 4)                        // ssbuf
             + al((size_t)(NWALL + 3 * 9 * CH3) * 2) + 4096;
    };
    int PG = 8;
    while (PG > 1 && need(PG) > ws_size) PG >>= 1;

    size_t off = 0;
    char* base = (char*)d_ws;
    auto alloc = [&](size_t bytes) -> char* {
        char* p = base + off;
        off = (off + bytes + 255) & ~(size_t)255;
        return p;
    };
    unsigned short* regionA = (unsigned short*)alloc((size_t)PG * HW * CH3 * 2);
    unsigned short* regionB = (unsigned short*)alloc((size_t)PG * HW * CH3 * 2);
    unsigned short* xng     = (unsigned short*)alloc((size_t)PG * HW * CDIM * 2);
    unsigned short* Apad    = (unsigned short*)alloc((size_t)PG * NHEADS * 48 * 64 * 2);
    float*          ssbuf   = (float*)alloc((size_t)PG * 384 * 4);
    unsigned short* wbf     = (unsigned short*)alloc((size_t)(NWALL + 3 * 9 * CH3) * 2);

    unsigned short* wq   = wbf;
    unsigned short* wpj  = wbf + NWQ;
    unsigned short* wpm  = wbf + NWQ + NWP;
    unsigned short* wpo  = wbf + NWQ + NWP + NWM;
    unsigned short* wdwT = wbf + NWALL;
    unsigned short* wd1T = wdwT + 9 * CH3;
    unsigned short* wd2T = wd1T + 9 * CH3;

    unsigned short* preQKV  = regionA;   // attn: [z][p][576]
    unsigned short* attnout = regionA;   // [z][p][192] (preQKV dead)
    unsigned short* f1      = regionA;   // ffn
    unsigned short* f3      = regionA;   // aliases f1 (dead after pm)
    unsigned short* qkvT    = regionB;
    unsigned short* f2      = regionB;
    float* G0p = (float*)xng;            // aliases xn (dead after qkv GEMM)

    dim3 blk(256);

    wcvt<<<dim3(162, 7), blk, 0, stream>>>(qkv_w, proj_w, pm_w, po_w,
                                           qdw_w, dw1_w, dw2_w,
                                           wbf, NWQ, NWP, NWM, NWO);

    for (int b0 = 0; b0 < NB; b0 += PG) {
        const float* xb = x + (size_t)b0 * CDIM * HW;
        float* x2b      = out + (size_t)b0 * CDIM * HW;

        // ---------- attention ----------
        zero_f<<<dim3((PG * 384 + 255) / 256), blk, 0, stream>>>(ssbuf, PG * 384);
        ln_norm<<<dim3(64, PG), blk, 0, stream>>>(xb, ln1w, ln1b, xng);
        gemm_nhwc<0, CDIM><<<dim3(128, 3, PG), blk, 0, stream>>>(
            wq, xng, qkv_b, preQKV, CH3);
        dwp_nhwc<<<dim3(64, 72, PG), blk, 0, stream>>>(
            preQKV, wdwT, qdw_b, prompt, qkvT, ssbuf);
        gram1<<<dim3(NSL2, NHEADS, PG), blk, 0, stream>>>(qkvT, G0p);
        softmax1<<<dim3(NHEADS, PG), blk, 0, stream>>>(G0p, ssbuf, temp, Apad);
        apply_pv<<<dim3(64, NHEADS, PG), blk, 0, stream>>>(qkvT, Apad, attnout);
        gemm_nchw<CDIM><<<dim3(128, 1, PG), blk, 0, stream>>>(
            wpj, attnout, proj_b, xb, x2b);

        // ---------- FFN ----------
        ln_norm<<<dim3(64, PG), blk, 0, stream>>>(x2b, ln2w, ln2b, xng);
        dw1_nhwc<<<dim3(64, 24, PG), blk, 0, stream>>>(xng, wd1T, dw1_b, f1);
        gemm_nhwc<1, CH3><<<dim3(128, 3, PG), blk, 0, stream>>>(
            wpm, f1, pm_b, f2, CH3);
        dw2_nhwc<<<dim3(64, 72, PG), blk, 0, stream>>>(f2, wd2T, dw2_b, f3);
        gemm_nchw<CH3><<<dim3(128, 1, PG), blk, 0, stream>>>(
            wpo, f3, po_b, x2b, x2b);
    }
}

// Round 8
// 1226.085 us; speedup vs baseline: 1.6183x; 1.4735x over previous
//
#include <hip/hip_runtime.h>

// Problem constants
#define HW     16384      // 128*128
#define NB     8
#define CDIM   192
#define CH3    576
#define NHEADS 4
#define CHH    48
#define NSL2   128        // gram pixel-slices (128 px each)
#define LDP    136        // gram LDS row stride
#define KT     64         // GEMM K-tile
#define LDK    72         // GEMM LDS row stride (36 dwords: banks at floor)

// Blocked C8 layout for bf16 intermediates: [c/8][pixel][8]
// addr(c, p) = (c>>3)*HW*8 + p*8 + (c&7)

typedef short  v8s  __attribute__((ext_vector_type(8)));
typedef float  v4f  __attribute__((ext_vector_type(4)));
typedef unsigned short u16x8 __attribute__((ext_vector_type(8)));

__device__ __forceinline__ float bf2f(unsigned short s) {
    return __uint_as_float(((unsigned)s) << 16);
}
__device__ __forceinline__ unsigned short f2bf(float f) {
    unsigned u = __float_as_uint(f);
    return (unsigned short)((u + 0x7fffu + ((u >> 16) & 1u)) >> 16);
}
__device__ __forceinline__ float gelu_f(float x) {
    return 0.5f * x * (1.0f + erff(x * 0.70710678118654752f));
}

// ---------------------------------------------------------------------------
// Weight prep: 4 GEMM mats fp32->bf16 packed; 3 depthwise mats transposed to
// [tap][576] bf16. grid (162, 7)
// ---------------------------------------------------------------------------
__global__ __launch_bounds__(256) void wcvt(const float* __restrict__ s0,
                                            const float* __restrict__ s1,
                                            const float* __restrict__ s2,
                                            const float* __restrict__ s3,
                                            const float* __restrict__ dq,
                                            const float* __restrict__ d1,
                                            const float* __restrict__ d2,
                                            unsigned short* __restrict__ d,
                                            int n0, int n1, int n2, int n3) {
    int y = blockIdx.y;
    if (y < 4) {
        const float* srcs[4] = {s0, s1, s2, s3};
        int cnts[4] = {n0, n1, n2, n3};
        int offs[4] = {0, n0, n0 + n1, n0 + n1 + n2};
        const float* s = srcs[y];
        unsigned short* o = d + offs[y];
        int i = (blockIdx.x * 256 + threadIdx.x) * 8;
        if (i + 8 <= cnts[y]) {
            float4 a = *(const float4*)(s + i);
            float4 b = *(const float4*)(s + i + 4);
            u16x8 u;
            u[0] = f2bf(a.x); u[1] = f2bf(a.y); u[2] = f2bf(a.z); u[3] = f2bf(a.w);
            u[4] = f2bf(b.x); u[5] = f2bf(b.y); u[6] = f2bf(b.z); u[7] = f2bf(b.w);
            *(u16x8*)(o + i) = u;
        }
    } else {
        const float* s = (y == 4) ? dq : (y == 5) ? d1 : d2;
        unsigned short* o = d + (n0 + n1 + n2 + n3) + (y - 4) * 9 * CH3;
        int i = blockIdx.x * 256 + threadIdx.x;
        if (i < 9 * CH3) {
            int tap = i / CH3, c = i - tap * CH3;
            o[i] = f2bf(s[c * 9 + tap]);
        }
    }
}

__global__ __launch_bounds__(256) void zero_f(float* __restrict__ p, int n) {
    int i = blockIdx.x * 256 + threadIdx.x;
    if (i < n) p[i] = 0.f;
}

// ---------------------------------------------------------------------------
// LayerNorm: NCHW fp32 in -> C8-blocked bf16 out. grid (64, Z)
// ---------------------------------------------------------------------------
__global__ __launch_bounds__(256) void ln_norm(const float* __restrict__ x,
                                               const float* __restrict__ lnw,
                                               const float* __restrict__ lnb,
                                               unsigned short* __restrict__ xn) {
    int p = blockIdx.x * 256 + threadIdx.x;
    int z = blockIdx.y;
    const float* xp = x + (size_t)z * CDIM * HW;
    float s = 0.f, ss = 0.f;
    for (int c = 0; c < CDIM; ++c) {
        float v = xp[(size_t)c * HW + p];
        s += v; ss += v * v;
    }
    float m = s * (1.0f / CDIM);
    float var = ss * (1.0f / CDIM) - m * m;
    float r = 1.0f / sqrtf(var + 1e-5f);
    unsigned short* op = xn + (size_t)z * HW * CDIM;
    for (int cg = 0; cg < CDIM / 8; ++cg) {
        u16x8 u;
#pragma unroll
        for (int j = 0; j < 8; ++j) {
            int c = cg * 8 + j;
            u[j] = f2bf((xp[(size_t)c * HW + p] - m) * r * lnw[c] + lnb[c]);
        }
        *(u16x8*)(op + (size_t)cg * HW * 8 + (size_t)p * 8) = u;
    }
}

// ---------------------------------------------------------------------------
// C8 GEMM, LDS-staged X: out[p][ch] = sum_k X[p][k]*W[ch][k], bf16 C8 out.
// Block 128px x 192ch, 4 waves (2px x 2ch), wave 64px x 96ch.
// X tile [128][KT] in LDS; staging loads are contiguous across the wave
// (consecutive threads -> consecutive pixels in a chunk). W direct global.
// EPI 0: +bias; 1: +bias+gelu. grid (128, M/192, Z)
// ---------------------------------------------------------------------------
template <int EPI, int K>
__global__ __launch_bounds__(256) void gemm_c8(
    const unsigned short* __restrict__ Wb,
    const unsigned short* __restrict__ X,
    const float* __restrict__ bias,
    unsigned short* __restrict__ out) {
    __shared__ unsigned short Xs[128 * LDK];
    const int t = threadIdx.x;
    const int p0 = blockIdx.x * 128, M0 = blockIdx.y * 192, z = blockIdx.z;
    const int wid = t >> 6, lane = t & 63, lm = lane & 15, quad = lane >> 4;
    const int wp = (wid & 1) * 64, wc = (wid >> 1) * 96;

    const unsigned short* Xz = X + (size_t)z * HW * K;
    // staging: thread covers pixel row t>>1, k-elems (t&1)*32 .. +31
    const int srow = t >> 1, shalf = (t & 1) * 32;
    const unsigned short* spz = Xz + (size_t)(p0 + srow) * 8;
    unsigned short* sd = &Xs[srow * LDK + shalf];

    v4f acc[4][6];
#pragma unroll
    for (int i = 0; i < 4; ++i)
#pragma unroll
        for (int j = 0; j < 6; ++j) acc[i][j] = (v4f)0.0f;

    const unsigned short* br[6];
#pragma unroll
    for (int j = 0; j < 6; ++j)
        br[j] = Wb + (size_t)(M0 + wc + j * 16 + lm) * K + quad * 8;

    for (int kt = 0; kt < K; kt += KT) {
        int cb = (kt + shalf) >> 3;
        u16x8 g0 = *(const u16x8*)(spz + (size_t)(cb + 0) * HW * 8);
        u16x8 g1 = *(const u16x8*)(spz + (size_t)(cb + 1) * HW * 8);
        u16x8 g2 = *(const u16x8*)(spz + (size_t)(cb + 2) * HW * 8);
        u16x8 g3 = *(const u16x8*)(spz + (size_t)(cb + 3) * HW * 8);
        if (kt) __syncthreads();
        *(u16x8*)sd = g0;
        *(u16x8*)(sd + 8) = g1;
        *(u16x8*)(sd + 16) = g2;
        *(u16x8*)(sd + 24) = g3;
        __syncthreads();
#pragma unroll
        for (int ks = 0; ks < 2; ++ks) {
            v8s a[4], b[6];
#pragma unroll
            for (int i = 0; i < 4; ++i)
                a[i] = *(const v8s*)&Xs[(wp + i * 16 + lm) * LDK + ks * 32 + quad * 8];
#pragma unroll
            for (int j = 0; j < 6; ++j)
                b[j] = *(const v8s*)(br[j] + kt + ks * 32);
#pragma unroll
            for (int i = 0; i < 4; ++i)
#pragma unroll
                for (int j = 0; j < 6; ++j)
                    acc[i][j] = __builtin_amdgcn_mfma_f32_16x16x32_bf16(a[i], b[j], acc[i][j], 0, 0, 0);
        }
    }

    unsigned short* Oz = out + (size_t)z * HW * (size_t)(EPI == 0 ? CH3 : CH3);
    // note: all C8-GEMM outputs here are 576-ch (qkv, pm)
#pragma unroll
    for (int i = 0; i < 4; ++i)
#pragma unroll
        for (int j = 0; j < 6; ++j) {
            int ch = M0 + wc + j * 16 + lm;
            int cg = ch >> 3, co = ch & 7;
            float bch = bias[ch];
#pragma unroll
            for (int r = 0; r < 4; ++r) {
                int p = p0 + wp + i * 16 + quad * 4 + r;
                float v = acc[i][j][r] + bch;
                if (EPI == 1) v = gelu_f(v);
                Oz[(size_t)cg * HW * 8 + (size_t)p * 8 + co] = f2bf(v);
            }
        }
}

// ---------------------------------------------------------------------------
// NCHW-output GEMM, LDS-staged C8 X: out[m][p] = sum_k W[m][k]*X[p][k] + res,
// fp32 NCHW. Block 192ch x 128px (all M), 4 waves (2ch x 2px). grid (128,1,Z)
// ---------------------------------------------------------------------------
template <int K>
__global__ __launch_bounds__(256) void gemm_nchw(
    const unsigned short* __restrict__ Wb,
    const unsigned short* __restrict__ X,
    const float* __restrict__ bias,
    const float* __restrict__ res,
    float* __restrict__ outp) {
    __shared__ unsigned short Xs[128 * LDK];
    const int t = threadIdx.x;
    const int p0 = blockIdx.x * 128, z = blockIdx.z;
    const int wid = t >> 6, lane = t & 63, lm = lane & 15, quad = lane >> 4;
    const int wm = (wid >> 1) * 96, wph = (wid & 1) * 64;

    const unsigned short* Xz = X + (size_t)z * HW * K;
    const int srow = t >> 1, shalf = (t & 1) * 32;
    const unsigned short* spz = Xz + (size_t)(p0 + srow) * 8;
    unsigned short* sd = &Xs[srow * LDK + shalf];

    v4f acc[6][4];
#pragma unroll
    for (int i = 0; i < 6; ++i)
#pragma unroll
        for (int j = 0; j < 4; ++j) acc[i][j] = (v4f)0.0f;

    const unsigned short* ar[6];
#pragma unroll
    for (int i = 0; i < 6; ++i)
        ar[i] = Wb + (size_t)(wm + i * 16 + lm) * K + quad * 8;

    for (int kt = 0; kt < K; kt += KT) {
        int cb = (kt + shalf) >> 3;
        u16x8 g0 = *(const u16x8*)(spz + (size_t)(cb + 0) * HW * 8);
        u16x8 g1 = *(const u16x8*)(spz + (size_t)(cb + 1) * HW * 8);
        u16x8 g2 = *(const u16x8*)(spz + (size_t)(cb + 2) * HW * 8);
        u16x8 g3 = *(const u16x8*)(spz + (size_t)(cb + 3) * HW * 8);
        if (kt) __syncthreads();
        *(u16x8*)sd = g0;
        *(u16x8*)(sd + 8) = g1;
        *(u16x8*)(sd + 16) = g2;
        *(u16x8*)(sd + 24) = g3;
        __syncthreads();
#pragma unroll
        for (int ks = 0; ks < 2; ++ks) {
            v8s a[6], b[4];
#pragma unroll
            for (int i = 0; i < 6; ++i)
                a[i] = *(const v8s*)(ar[i] + kt + ks * 32);
#pragma unroll
            for (int j = 0; j < 4; ++j)
                b[j] = *(const v8s*)&Xs[(wph + j * 16 + lm) * LDK + ks * 32 + quad * 8];
#pragma unroll
            for (int i = 0; i < 6; ++i)
#pragma unroll
                for (int j = 0; j < 4; ++j)
                    acc[i][j] = __builtin_amdgcn_mfma_f32_16x16x32_bf16(a[i], b[j], acc[i][j], 0, 0, 0);
        }
    }

#pragma unroll
    for (int i = 0; i < 6; ++i)
#pragma unroll
        for (int j = 0; j < 4; ++j) {
            int gp = p0 + wph + j * 16 + lm;
#pragma unroll
            for (int r = 0; r < 4; ++r) {
                int gm = wm + i * 16 + quad * 4 + r;
                size_t oi = (size_t)z * CDIM * HW + (size_t)gm * HW + gp;
                outp[oi] = acc[i][j][r] + bias[gm] + res[oi];
            }
        }
}

// ---------------------------------------------------------------------------
// Depthwise 3x3 + bias + prompt on C8 576ch, 8 ch/thread, fused sum-sq
// atomics for q,k channels. grid (64, 72, Z). Coalesced: wave = 64 px x 16B.
// ---------------------------------------------------------------------------
__global__ __launch_bounds__(256) void dwp_c8(const unsigned short* __restrict__ in,
                                              const unsigned short* __restrict__ wT,
                                              const float* __restrict__ b1,
                                              const float* __restrict__ prompt,
                                              unsigned short* __restrict__ out,
                                              float* __restrict__ ssbuf) {
    int t = threadIdx.x;
    int px = blockIdx.x * 256 + t;
    int cg = blockIdx.y, c0 = cg * 8;
    int z = blockIdx.z;
    int h = px >> 7, w = px & 127;
    const unsigned short* ip = in + (size_t)z * HW * CH3 + (size_t)cg * HW * 8;
    int pc = c0 % CDIM;
    float acc[8];
#pragma unroll
    for (int j = 0; j < 8; ++j) acc[j] = b1[c0 + j] + prompt[pc + j];
#pragma unroll
    for (int ky = 0; ky < 3; ++ky) {
        int hy = h + ky - 1;
        if ((unsigned)hy >= 128u) continue;
#pragma unroll
        for (int kx = 0; kx < 3; ++kx) {
            int wx = w + kx - 1;
            if ((unsigned)wx >= 128u) continue;
            u16x8 xv = *(const u16x8*)(ip + (size_t)((hy << 7) + wx) * 8);
            u16x8 wv = *(const u16x8*)(wT + (ky * 3 + kx) * CH3 + c0);
#pragma unroll
            for (int j = 0; j < 8; ++j) acc[j] = fmaf(bf2f(wv[j]), bf2f(xv[j]), acc[j]);
        }
    }
    u16x8 o;
    float sl[8];
#pragma unroll
    for (int j = 0; j < 8; ++j) {
        unsigned short q = f2bf(acc[j]);
        o[j] = q;
        float vr = bf2f(q);
        sl[j] = vr * vr;
    }
    *(u16x8*)(out + (size_t)z * HW * CH3 + (size_t)cg * HW * 8 + (size_t)px * 8) = o;

    if (c0 < 384) {   // q,k channels: accumulate sum-squares
        int wid = t >> 6, lane = t & 63;
#pragma unroll
        for (int j = 0; j < 8; ++j)
            for (int off = 32; off; off >>= 1) sl[j] += __shfl_down(sl[j], off);
        __shared__ float wr[4][8];
        if (lane == 0)
#pragma unroll
            for (int j = 0; j < 8; ++j) wr[wid][j] = sl[j];
        __syncthreads();
        if (t < 8) {
            float s = wr[0][t] + wr[1][t] + wr[2][t] + wr[3][t];
            atomicAdd(&ssbuf[z * 384 + c0 + t], s);
        }
    }
}

// ---------------------------------------------------------------------------
// Gram partials: G[cq][ck] = sum_p q[p][cq]*k[p][ck] per 128-px slice.
// LDS transpose-stage C8 -> [c][p], then MFMA (waves split p). grid (128,4,Z)
// ---------------------------------------------------------------------------
__global__ __launch_bounds__(256) void gram1(const unsigned short* __restrict__ qkvT,
                                             float* __restrict__ G0p) {
    const int sl = blockIdx.x, hh = blockIdx.y, z = blockIdx.z;
    const int t = threadIdx.x;
    const int wid = t >> 6, lane = t & 63, lm = lane & 15, quad = lane >> 4;

    __shared__ float Gs[4][2304];                       // 36.9 KB, aliased below
    unsigned short* qs = (unsigned short*)&Gs[0][0];    // [48][LDP]
    unsigned short* ks = qs + 48 * LDP;

    const unsigned short* bz = qkvT + (size_t)z * HW * CH3;
    int half = t & 1, pl = t >> 1;
    size_t pofs = (size_t)(sl * 128 + pl) * 8;
#pragma unroll
    for (int ci = 0; ci < 3; ++ci) {
        int cg = half * 3 + ci;                          // 0..5 within head
        u16x8 uq = *(const u16x8*)(bz + (size_t)(hh * 6 + cg) * HW * 8 + pofs);
        u16x8 uk = *(const u16x8*)(bz + (size_t)(24 + hh * 6 + cg) * HW * 8 + pofs);
#pragma unroll
        for (int j = 0; j < 8; ++j) {
            qs[(cg * 8 + j) * LDP + pl] = uq[j];
            ks[(cg * 8 + j) * LDP + pl] = uk[j];
        }
    }
    __syncthreads();

    v4f acc[3][3];
#pragma unroll
    for (int mi = 0; mi < 3; ++mi)
#pragma unroll
        for (int ni = 0; ni < 3; ++ni) acc[mi][ni] = (v4f)0.0f;

    int kp = wid * 32;    // each wave one p-quarter
    v8s a[3], b[3];
#pragma unroll
    for (int i = 0; i < 3; ++i) {
        a[i] = *(const v8s*)&qs[(i * 16 + lm) * LDP + kp + quad * 8];
        b[i] = *(const v8s*)&ks[(i * 16 + lm) * LDP + kp + quad * 8];
    }
#pragma unroll
    for (int mi = 0; mi < 3; ++mi)
#pragma unroll
        for (int ni = 0; ni < 3; ++ni)
            acc[mi][ni] = __builtin_amdgcn_mfma_f32_16x16x32_bf16(a[mi], b[ni], acc[mi][ni], 0, 0, 0);

    __syncthreads();   // staged data consumed; safe to overwrite with Gs
#pragma unroll
    for (int mi = 0; mi < 3; ++mi)
#pragma unroll
        for (int ni = 0; ni < 3; ++ni)
#pragma unroll
            for (int r = 0; r < 4; ++r)
                Gs[wid][(mi * 16 + quad * 4 + r) * 48 + ni * 16 + lm] = acc[mi][ni][r];
    __syncthreads();
    float* gp = G0p + (((size_t)z * NHEADS + hh) * NSL2 + sl) * 2304;
    for (int i = t; i < 2304; i += 256)
        gp[i] = Gs[0][i] + Gs[1][i] + Gs[2][i] + Gs[3][i];
}

// ---------------------------------------------------------------------------
// softmax over d with inline inv-norms; outputs bf16 A zero-padded [48][64].
// grid (4, Z) x 256
// ---------------------------------------------------------------------------
__global__ __launch_bounds__(256) void softmax1(const float* __restrict__ G0p,
                                                const float* __restrict__ ssbuf,
                                                const float* __restrict__ temp,
                                                unsigned short* __restrict__ Apad) {
    int hh = blockIdx.x, z = blockIdx.y, t = threadIdx.x;
    __shared__ float Gsum[2304];
    const float* gb = G0p + ((size_t)z * NHEADS + hh) * NSL2 * 2304;
    for (int i = t; i < 2304; i += 256) {
        float s = 0.f;
#pragma unroll 8
        for (int sl = 0; sl < NSL2; ++sl) s += gb[(size_t)sl * 2304 + i];
        Gsum[i] = s;
    }
    __syncthreads();
    if (t < 48) {
        float T = temp[hh];
        const float* sb = ssbuf + z * 384;
        float invq = 1.0f / fmaxf(sqrtf(sb[hh * CHH + t]), 1e-12f);
        float lg[48];
        float mx = -1e30f;
#pragma unroll
        for (int d = 0; d < 48; ++d) {
            float invk = 1.0f / fmaxf(sqrtf(sb[192 + hh * CHH + d]), 1e-12f);
            float l = T * Gsum[t * 48 + d] * invq * invk;
            lg[d] = l;
            mx = fmaxf(mx, l);
        }
        float sum = 0.f;
#pragma unroll
        for (int d = 0; d < 48; ++d) { float e = expf(lg[d] - mx); lg[d] = e; sum += e; }
        float inv = 1.0f / sum;
        unsigned short* ap = Apad + ((size_t)z * NHEADS + hh) * 48 * 64 + t * 64;
#pragma unroll
        for (int d = 0; d < 48; ++d) ap[d] = f2bf(lg[d] * inv);
#pragma unroll
        for (int d = 48; d < 64; ++d) ap[d] = 0;
    }
}

// ---------------------------------------------------------------------------
// PV apply via MFMA: out[p][c] = sum_d V[p][d]*A[c][d]. V C8 direct (chunk
// clamped for the zero-padded k=48..63 -> finite junk x 0); A bf16 [48][64].
// grid (64, 4, Z)
// ---------------------------------------------------------------------------
__global__ __launch_bounds__(256) void apply_pv(const unsigned short* __restrict__ qkvT,
                                                const unsigned short* __restrict__ Apad,
                                                unsigned short* __restrict__ attnout) {
    const int t = threadIdx.x;
    const int hh = blockIdx.y, z = blockIdx.z;
    const int wid = t >> 6, lane = t & 63, lm = lane & 15, quad = lane >> 4;
    const int p0 = blockIdx.x * 256 + wid * 64;

    const unsigned short* bz = qkvT + (size_t)z * HW * CH3;
    const unsigned short* Ab = Apad + ((size_t)z * NHEADS + hh) * 48 * 64;

    v4f acc[4][3];
#pragma unroll
    for (int i = 0; i < 4; ++i)
#pragma unroll
        for (int j = 0; j < 3; ++j) acc[i][j] = (v4f)0.0f;

#pragma unroll
    for (int ks = 0; ks < 2; ++ks) {
        int cgv = 48 + hh * 6 + ks * 4 + quad;     // V chunk; >head range when k>=48
        if (cgv > 71) cgv = 71;                     // clamp: finite junk x A-pad zeros
        const unsigned short* vp = bz + (size_t)cgv * HW * 8;
        v8s a[4], b[3];
#pragma unroll
        for (int i = 0; i < 4; ++i)
            a[i] = *(const v8s*)(vp + (size_t)(p0 + i * 16 + lm) * 8);
#pragma unroll
        for (int j = 0; j < 3; ++j)
            b[j] = *(const v8s*)(Ab + (j * 16 + lm) * 64 + ks * 32 + quad * 8);
#pragma unroll
        for (int i = 0; i < 4; ++i)
#pragma unroll
            for (int j = 0; j < 3; ++j)
                acc[i][j] = __builtin_amdgcn_mfma_f32_16x16x32_bf16(a[i], b[j], acc[i][j], 0, 0, 0);
    }

    unsigned short* Oz = attnout + (size_t)z * HW * CDIM;
#pragma unroll
    for (int i = 0; i < 4; ++i)
#pragma unroll
        for (int j = 0; j < 3; ++j) {
            int ch = hh * CHH + j * 16 + lm;
            int cg = ch >> 3, co = ch & 7;
#pragma unroll
            for (int r = 0; r < 4; ++r) {
                int p = p0 + i * 16 + quad * 4 + r;
                Oz[(size_t)cg * HW * 8 + (size_t)p * 8 + co] = f2bf(acc[i][j][r]);
            }
        }
}

// ---------------------------------------------------------------------------
// FFN grouped 3x3 (192->576) C8: 1 input chunk -> 3 output chunks per thread.
// grid (64, 24, Z)
// ---------------------------------------------------------------------------
__global__ __launch_bounds__(256) void dw1_c8(const unsigned short* __restrict__ xn,
                                              const unsigned short* __restrict__ wT,
                                              const float* __restrict__ b1,
                                              unsigned short* __restrict__ f1) {
    int t = threadIdx.x;
    int px = blockIdx.x * 256 + t;
    int gin = blockIdx.y;            // input chunk 0..23
    int c0 = gin * 24;               // first of 24 output channels
    int z = blockIdx.z;
    int h = px >> 7, w = px & 127;
    const unsigned short* ip = xn + (size_t)z * HW * CDIM + (size_t)gin * HW * 8;
    float acc[24];
#pragma unroll
    for (int j = 0; j < 24; ++j) acc[j] = b1[c0 + j];
#pragma unroll
    for (int ky = 0; ky < 3; ++ky) {
        int hy = h + ky - 1;
        if ((unsigned)hy >= 128u) continue;
#pragma unroll
        for (int kx = 0; kx < 3; ++kx) {
            int wx = w + kx - 1;
            if ((unsigned)wx >= 128u) continue;
            u16x8 xv = *(const u16x8*)(ip + (size_t)((hy << 7) + wx) * 8);
            float mv[8];
#pragma unroll
            for (int j = 0; j < 8; ++j) mv[j] = bf2f(xv[j]);
            const unsigned short* wp = wT + (ky * 3 + kx) * CH3 + c0;
            u16x8 w0 = *(const u16x8*)wp;
            u16x8 w1 = *(const u16x8*)(wp + 8);
            u16x8 w2 = *(const u16x8*)(wp + 16);
            float wv[24];
#pragma unroll
            for (int j = 0; j < 8; ++j) {
                wv[j] = bf2f(w0[j]); wv[8 + j] = bf2f(w1[j]); wv[16 + j] = bf2f(w2[j]);
            }
#pragma unroll
            for (int j = 0; j < 24; ++j) acc[j] = fmaf(wv[j], mv[j / 3], acc[j]);
        }
    }
    unsigned short* f1z = f1 + (size_t)z * HW * CH3;
#pragma unroll
    for (int q8 = 0; q8 < 3; ++q8) {
        u16x8 o;
#pragma unroll
        for (int j = 0; j < 8; ++j) o[j] = f2bf(acc[q8 * 8 + j]);
        *(u16x8*)(f1z + (size_t)(gin * 3 + q8) * HW * 8 + (size_t)px * 8) = o;
    }
}

// ---------------------------------------------------------------------------
// Depthwise 3x3 C8 576ch (FFN dw2). grid (64, 72, Z)
// ---------------------------------------------------------------------------
__global__ __launch_bounds__(256) void dw2_c8(const unsigned short* __restrict__ in,
                                              const unsigned short* __restrict__ wT,
                                              const float* __restrict__ b1,
                                              unsigned short* __restrict__ out) {
    int t = threadIdx.x;
    int px = blockIdx.x * 256 + t;
    int cg = blockIdx.y, c0 = cg * 8;
    int z = blockIdx.z;
    int h = px >> 7, w = px & 127;
    const unsigned short* ip = in + (size_t)z * HW * CH3 + (size_t)cg * HW * 8;
    float acc[8];
#pragma unroll
    for (int j = 0; j < 8; ++j) acc[j] = b1[c0 + j];
#pragma unroll
    for (int ky = 0; ky < 3; ++ky) {
        int hy = h + ky - 1;
        if ((unsigned)hy >= 128u) continue;
#pragma unroll
        for (int kx = 0; kx < 3; ++kx) {
            int wx = w + kx - 1;
            if ((unsigned)wx >= 128u) continue;
            u16x8 xv = *(const u16x8*)(ip + (size_t)((hy << 7) + wx) * 8);
            u16x8 wv = *(const u16x8*)(wT + (ky * 3 + kx) * CH3 + c0);
#pragma unroll
            for (int j = 0; j < 8; ++j) acc[j] = fmaf(bf2f(wv[j]), bf2f(xv[j]), acc[j]);
        }
    }
    u16x8 o;
#pragma unroll
    for (int j = 0; j < 8; ++j) o[j] = f2bf(acc[j]);
    *(u16x8*)(out + (size_t)z * HW * CH3 + (size_t)cg * HW * 8 + (size_t)px * 8) = o;
}

// ---------------------------------------------------------------------------
extern "C" void kernel_launch(void* const* d_in, const int* in_sizes, int n_in,
                              void* d_out, int out_size, void* d_ws, size_t ws_size,
                              hipStream_t stream) {
    const float* x      = (const float*)d_in[0];
    const float* ln1w   = (const float*)d_in[1];
    const float* ln1b   = (const float*)d_in[2];
    const float* qkv_w  = (const float*)d_in[3];
    const float* qkv_b  = (const float*)d_in[4];
    const float* qdw_w  = (const float*)d_in[5];
    const float* qdw_b  = (const float*)d_in[6];
    const float* temp   = (const float*)d_in[7];
    const float* prompt = (const float*)d_in[8];
    const float* proj_w = (const float*)d_in[9];
    const float* proj_b = (const float*)d_in[10];
    const float* ln2w   = (const float*)d_in[11];
    const float* ln2b   = (const float*)d_in[12];
    const float* dw1_w  = (const float*)d_in[13];
    const float* dw1_b  = (const float*)d_in[14];
    const float* pm_w   = (const float*)d_in[15];
    const float* pm_b   = (const float*)d_in[16];
    const float* dw2_w  = (const float*)d_in[17];
    const float* dw2_b  = (const float*)d_in[18];
    const float* po_w   = (const float*)d_in[19];
    const float* po_b   = (const float*)d_in[20];
    float* out = (float*)d_out;
    (void)in_sizes; (void)n_in; (void)out_size;

    const int NWQ = CH3 * CDIM, NWP = CDIM * CDIM, NWM = CH3 * CH3, NWO = CDIM * CH3;
    const int NWALL = NWQ + NWP + NWM + NWO;

    auto al = [](size_t b) { return (b + 255) & ~(size_t)255; };
    auto need = [&](int PG) -> size_t {
        return 2 * al((size_t)PG * HW * CH3 * 2)              // regionA, regionB
             + al((size_t)PG * HW * CDIM * 2)                  // xn / G0p union
             + al((size_t)PG * NHEADS * 48 * 64 * 2)           // Apad
             + al((size_t)PG * 384 * 4)                        // ssbuf
             + al((size_t)(NWALL + 3 * 9 * CH3) * 2) + 4096;
    };
    int PG = 8;
    while (PG > 1 && need(PG) > ws_size) PG >>= 1;

    size_t off = 0;
    char* base = (char*)d_ws;
    auto alloc = [&](size_t bytes) -> char* {
        char* p = base + off;
        off = (off + bytes + 255) & ~(size_t)255;
        return p;
    };
    unsigned short* regionA = (unsigned short*)alloc((size_t)PG * HW * CH3 * 2);
    unsigned short* regionB = (unsigned short*)alloc((size_t)PG * HW * CH3 * 2);
    unsigned short* xng     = (unsigned short*)alloc((size_t)PG * HW * CDIM * 2);
    unsigned short* Apad    = (unsigned short*)alloc((size_t)PG * NHEADS * 48 * 64 * 2);
    float*          ssbuf   = (float*)alloc((size_t)PG * 384 * 4);
    unsigned short* wbf     = (unsigned short*)alloc((size_t)(NWALL + 3 * 9 * CH3) * 2);

    unsigned short* wq   = wbf;
    unsigned short* wpj  = wbf + NWQ;
    unsigned short* wpm  = wbf + NWQ + NWP;
    unsigned short* wpo  = wbf + NWQ + NWP + NWM;
    unsigned short* wdwT = wbf + NWALL;
    unsigned short* wd1T = wdwT + 9 * CH3;
    unsigned short* wd2T = wd1T + 9 * CH3;

    unsigned short* preQKV  = regionA;   // attn: C8 [z][72][HW][8]
    unsigned short* attnout = regionA;   // C8 [z][24][HW][8] (preQKV dead)
    unsigned short* f1      = regionA;   // ffn C8
    unsigned short* f3      = regionA;   // aliases f1 (dead after pm)
    unsigned short* qkvT    = regionB;
    unsigned short* f2      = regionB;
    float* G0p = (float*)xng;            // aliases xn (dead after qkv GEMM)

    dim3 blk(256);

    wcvt<<<dim3(162, 7), blk, 0, stream>>>(qkv_w, proj_w, pm_w, po_w,
                                           qdw_w, dw1_w, dw2_w,
                                           wbf, NWQ, NWP, NWM, NWO);

    for (int b0 = 0; b0 < NB; b0 += PG) {
        const float* xb = x + (size_t)b0 * CDIM * HW;
        float* x2b      = out + (size_t)b0 * CDIM * HW;

        // ---------- attention ----------
        zero_f<<<dim3((PG * 384 + 255) / 256), blk, 0, stream>>>(ssbuf, PG * 384);
        ln_norm<<<dim3(64, PG), blk, 0, stream>>>(xb, ln1w, ln1b, xng);
        gemm_c8<0, CDIM><<<dim3(128, 3, PG), blk, 0, stream>>>(
            wq, xng, qkv_b, preQKV);
        dwp_c8<<<dim3(64, 72, PG), blk, 0, stream>>>(
            preQKV, wdwT, qdw_b, prompt, qkvT, ssbuf);
        gram1<<<dim3(NSL2, NHEADS, PG), blk, 0, stream>>>(qkvT, G0p);
        softmax1<<<dim3(NHEADS, PG), blk, 0, stream>>>(G0p, ssbuf, temp, Apad);
        apply_pv<<<dim3(64, NHEADS, PG), blk, 0, stream>>>(qkvT, Apad, attnout);
        gemm_nchw<CDIM><<<dim3(128, 1, PG), blk, 0, stream>>>(
            wpj, attnout, proj_b, xb, x2b);

        // ---------- FFN ----------
        ln_norm<<<dim3(64, PG), blk, 0, stream>>>(x2b, ln2w, ln2b, xng);
        dw1_c8<<<dim3(64, 24, PG), blk, 0, stream>>>(xng, wd1T, dw1_b, f1);
        gemm_c8<1, CH3><<<dim3(128, 3, PG), blk, 0, stream>>>(
            wpm, f1, pm_b, f2);
        dw2_c8<<<dim3(64, 72, PG), blk, 0, stream>>>(f2, wd2T, dw2_b, f3);
        gemm_nchw<CH3><<<dim3(128, 1, PG), blk, 0, stream>>>(
            wpo, f3, po_b, x2b, x2b);
    }
}

// Round 9
// 1120.787 us; speedup vs baseline: 1.7703x; 1.0940x over previous
//
#include <hip/hip_runtime.h>

// Problem constants
#define HW     16384      // 128*128
#define NB     8
#define CDIM   192
#define CH3    576
#define NHEADS 4
#define CHH    48
#define NSL2   128        // gram pixel-slices (128 px each)
#define LDP    136        // gram LDS row stride

// Blocked C8 layout for bf16 intermediates: [c/8][pixel][8]
// Packed-fragment weight layout: [tile_m][tile_k][lane][8],
//   lane=quad*16+lm holds W[tile_m*16+lm][tile_k*32+quad*8 .. +8]
//   -> one wave b-fragment load = 1KB contiguous.

typedef short  v8s  __attribute__((ext_vector_type(8)));
typedef float  v4f  __attribute__((ext_vector_type(4)));
typedef unsigned short u16x8 __attribute__((ext_vector_type(8)));

__device__ __forceinline__ float bf2f(unsigned short s) {
    return __uint_as_float(((unsigned)s) << 16);
}
__device__ __forceinline__ unsigned short f2bf(float f) {
    unsigned u = __float_as_uint(f);
    return (unsigned short)((u + 0x7fffu + ((u >> 16) & 1u)) >> 16);
}
__device__ __forceinline__ float gelu_f(float x) {
    return 0.5f * x * (1.0f + erff(x * 0.70710678118654752f));
}

// ---------------------------------------------------------------------------
// Weight prep: 4 GEMM mats fp32 -> bf16 packed FRAGMENT-TILED; 3 depthwise
// mats transposed to [tap][576] bf16. grid (162, 7)
// ---------------------------------------------------------------------------
__global__ __launch_bounds__(256) void wcvt(const float* __restrict__ s0,
                                            const float* __restrict__ s1,
                                            const float* __restrict__ s2,
                                            const float* __restrict__ s3,
                                            const float* __restrict__ dq,
                                            const float* __restrict__ d1,
                                            const float* __restrict__ d2,
                                            unsigned short* __restrict__ d,
                                            int n0, int n1, int n2, int n3) {
    int y = blockIdx.y;
    if (y < 4) {
        const float* srcs[4] = {s0, s1, s2, s3};
        const int Ms[4] = {CH3, CDIM, CH3, CDIM};
        const int Ks[4] = {CDIM, CDIM, CH3, CH3};
        int offs[4] = {0, n0, n0 + n1, n0 + n1 + n2};
        const float* s = srcs[y];
        unsigned short* o = d + offs[y];
        int M = Ms[y], K = Ks[y];
        int i = blockIdx.x * 256 + threadIdx.x;
        int total = M * K / 8;
        if (i < total) {
            int tiles_k = K / 32;
            int tm = i / (tiles_k * 64);
            int rem = i - tm * (tiles_k * 64);
            int tk = rem >> 6, lane = rem & 63;
            int quad = lane >> 4, lm = lane & 15;
            const float* sp = s + (size_t)(tm * 16 + lm) * K + tk * 32 + quad * 8;
            float4 a = *(const float4*)sp;
            float4 b = *(const float4*)(sp + 4);
            u16x8 u;
            u[0] = f2bf(a.x); u[1] = f2bf(a.y); u[2] = f2bf(a.z); u[3] = f2bf(a.w);
            u[4] = f2bf(b.x); u[5] = f2bf(b.y); u[6] = f2bf(b.z); u[7] = f2bf(b.w);
            *(u16x8*)(o + (size_t)i * 8) = u;
        }
    } else {
        const float* s = (y == 4) ? dq : (y == 5) ? d1 : d2;
        unsigned short* o = d + (n0 + n1 + n2 + n3) + (y - 4) * 9 * CH3;
        int i = blockIdx.x * 256 + threadIdx.x;
        if (i < 9 * CH3) {
            int tap = i / CH3, c = i - tap * CH3;
            o[i] = f2bf(s[c * 9 + tap]);
        }
    }
}

__global__ __launch_bounds__(256) void zero_f(float* __restrict__ p, int n) {
    int i = blockIdx.x * 256 + threadIdx.x;
    if (i < n) p[i] = 0.f;
}

// ---------------------------------------------------------------------------
// LayerNorm: NCHW fp32 in -> C8-blocked bf16 out. grid (64, Z)
// ---------------------------------------------------------------------------
__global__ __launch_bounds__(256) void ln_norm(const float* __restrict__ x,
                                               const float* __restrict__ lnw,
                                               const float* __restrict__ lnb,
                                               unsigned short* __restrict__ xn) {
    int p = blockIdx.x * 256 + threadIdx.x;
    int z = blockIdx.y;
    const float* xp = x + (size_t)z * CDIM * HW;
    float s = 0.f, ss = 0.f;
    for (int c = 0; c < CDIM; ++c) {
        float v = xp[(size_t)c * HW + p];
        s += v; ss += v * v;
    }
    float m = s * (1.0f / CDIM);
    float var = ss * (1.0f / CDIM) - m * m;
    float r = 1.0f / sqrtf(var + 1e-5f);
    unsigned short* op = xn + (size_t)z * HW * CDIM;
    for (int cg = 0; cg < CDIM / 8; ++cg) {
        u16x8 u;
#pragma unroll
        for (int j = 0; j < 8; ++j) {
            int c = cg * 8 + j;
            u[j] = f2bf((xp[(size_t)c * HW + p] - m) * r * lnw[c] + lnb[c]);
        }
        *(u16x8*)(op + (size_t)cg * HW * 8 + (size_t)p * 8) = u;
    }
}

// ---------------------------------------------------------------------------
// C8 GEMM, NO LDS/barriers: out[p][ch] = sum_k X[p][k]*W[ch][k], bf16 C8 out.
// Block 128px x 192ch, 4 waves (2px x 2ch), wave 64px x 96ch.
// X frags direct from C8 (16 lanes x 16B contiguous per quad); W frags from
// fragment-packed layout (1KB contiguous per wave-load, L2/L1-hot).
// EPI 0: +bias; 1: +bias+gelu. grid (128, M/192, Z)
// ---------------------------------------------------------------------------
template <int EPI, int K>
__global__ __launch_bounds__(256) void gemm_c8(
    const unsigned short* __restrict__ Wp,
    const unsigned short* __restrict__ X,
    const float* __restrict__ bias,
    unsigned short* __restrict__ out) {
    const int t = threadIdx.x;
    const int p0 = blockIdx.x * 128, M0 = blockIdx.y * 192, z = blockIdx.z;
    const int wid = t >> 6, lane = t & 63, lm = lane & 15, quad = lane >> 4;
    const int wp = (wid & 1) * 64, wc = (wid >> 1) * 96;
    constexpr int TK = K / 32;

    const unsigned short* Xz = X + (size_t)z * HW * K;
    const unsigned short* xa = Xz + (size_t)(p0 + wp + lm) * 8 + (size_t)quad * HW * 8;
    const unsigned short* bw = Wp + ((size_t)((M0 + wc) >> 4) * TK) * 512 + lane * 8;

    v4f acc[4][6];
#pragma unroll
    for (int i = 0; i < 4; ++i)
#pragma unroll
        for (int j = 0; j < 6; ++j) acc[i][j] = (v4f)0.0f;

#pragma unroll 2
    for (int kt = 0; kt < K; kt += 32) {
        const unsigned short* xk = xa + (size_t)(kt >> 3) * HW * 8;
        v8s a[4], b[6];
#pragma unroll
        for (int i = 0; i < 4; ++i)
            a[i] = *(const v8s*)(xk + i * 128);
#pragma unroll
        for (int j = 0; j < 6; ++j)
            b[j] = *(const v8s*)(bw + ((size_t)j * TK + (kt >> 5)) * 512);
#pragma unroll
        for (int i = 0; i < 4; ++i)
#pragma unroll
            for (int j = 0; j < 6; ++j)
                acc[i][j] = __builtin_amdgcn_mfma_f32_16x16x32_bf16(a[i], b[j], acc[i][j], 0, 0, 0);
    }

    unsigned short* Oz = out + (size_t)z * HW * CH3;
#pragma unroll
    for (int i = 0; i < 4; ++i)
#pragma unroll
        for (int j = 0; j < 6; ++j) {
            int ch = M0 + wc + j * 16 + lm;
            int cg = ch >> 3, co = ch & 7;
            float bch = bias[ch];
#pragma unroll
            for (int r = 0; r < 4; ++r) {
                int p = p0 + wp + i * 16 + quad * 4 + r;
                float v = acc[i][j][r] + bch;
                if (EPI == 1) v = gelu_f(v);
                Oz[(size_t)cg * HW * 8 + (size_t)p * 8 + co] = f2bf(v);
            }
        }
}

// ---------------------------------------------------------------------------
// NCHW-output GEMM, NO LDS: out[m][p] = sum_k W[m][k]*X[p][k] + res, fp32.
// Block 192ch x 128px (all M), 4 waves (2ch x 2px), wave 96x64.
// W frags fragment-packed; X frags direct C8. grid (128, 1, Z)
// ---------------------------------------------------------------------------
template <int K>
__global__ __launch_bounds__(256) void gemm_nchw(
    const unsigned short* __restrict__ Wp,
    const unsigned short* __restrict__ X,
    const float* __restrict__ bias,
    const float* __restrict__ res,
    float* __restrict__ outp) {
    const int t = threadIdx.x;
    const int p0 = blockIdx.x * 128, z = blockIdx.z;
    const int wid = t >> 6, lane = t & 63, lm = lane & 15, quad = lane >> 4;
    const int wm = (wid >> 1) * 96, wph = (wid & 1) * 64;
    constexpr int TK = K / 32;

    const unsigned short* Xz = X + (size_t)z * HW * K;
    const unsigned short* xb = Xz + (size_t)(p0 + wph + lm) * 8 + (size_t)quad * HW * 8;
    const unsigned short* aw = Wp + ((size_t)(wm >> 4) * TK) * 512 + lane * 8;

    v4f acc[6][4];
#pragma unroll
    for (int i = 0; i < 6; ++i)
#pragma unroll
        for (int j = 0; j < 4; ++j) acc[i][j] = (v4f)0.0f;

#pragma unroll 2
    for (int kt = 0; kt < K; kt += 32) {
        const unsigned short* xk = xb + (size_t)(kt >> 3) * HW * 8;
        v8s a[6], b[4];
#pragma unroll
        for (int i = 0; i < 6; ++i)
            a[i] = *(const v8s*)(aw + ((size_t)i * TK + (kt >> 5)) * 512);
#pragma unroll
        for (int j = 0; j < 4; ++j)
            b[j] = *(const v8s*)(xk + j * 128);
#pragma unroll
        for (int i = 0; i < 6; ++i)
#pragma unroll
            for (int j = 0; j < 4; ++j)
                acc[i][j] = __builtin_amdgcn_mfma_f32_16x16x32_bf16(a[i], b[j], acc[i][j], 0, 0, 0);
    }

#pragma unroll
    for (int i = 0; i < 6; ++i)
#pragma unroll
        for (int j = 0; j < 4; ++j) {
            int gp = p0 + wph + j * 16 + lm;
#pragma unroll
            for (int r = 0; r < 4; ++r) {
                int gm = wm + i * 16 + quad * 4 + r;
                size_t oi = (size_t)z * CDIM * HW + (size_t)gm * HW + gp;
                outp[oi] = acc[i][j][r] + bias[gm] + res[oi];
            }
        }
}

// ---------------------------------------------------------------------------
// Depthwise 3x3 + bias + prompt on C8 576ch, 8 ch/thread, fused sum-sq
// atomics for q,k channels. grid (64, 72, Z). Coalesced: wave = 64 px x 16B.
// ---------------------------------------------------------------------------
__global__ __launch_bounds__(256) void dwp_c8(const unsigned short* __restrict__ in,
                                              const unsigned short* __restrict__ wT,
                                              const float* __restrict__ b1,
                                              const float* __restrict__ prompt,
                                              unsigned short* __restrict__ out,
                                              float* __restrict__ ssbuf) {
    int t = threadIdx.x;
    int px = blockIdx.x * 256 + t;
    int cg = blockIdx.y, c0 = cg * 8;
    int z = blockIdx.z;
    int h = px >> 7, w = px & 127;
    const unsigned short* ip = in + (size_t)z * HW * CH3 + (size_t)cg * HW * 8;
    int pc = c0 % CDIM;
    float acc[8];
#pragma unroll
    for (int j = 0; j < 8; ++j) acc[j] = b1[c0 + j] + prompt[pc + j];
#pragma unroll
    for (int ky = 0; ky < 3; ++ky) {
        int hy = h + ky - 1;
        if ((unsigned)hy >= 128u) continue;
#pragma unroll
        for (int kx = 0; kx < 3; ++kx) {
            int wx = w + kx - 1;
            if ((unsigned)wx >= 128u) continue;
            u16x8 xv = *(const u16x8*)(ip + (size_t)((hy << 7) + wx) * 8);
            u16x8 wv = *(const u16x8*)(wT + (ky * 3 + kx) * CH3 + c0);
#pragma unroll
            for (int j = 0; j < 8; ++j) acc[j] = fmaf(bf2f(wv[j]), bf2f(xv[j]), acc[j]);
        }
    }
    u16x8 o;
    float sl[8];
#pragma unroll
    for (int j = 0; j < 8; ++j) {
        unsigned short q = f2bf(acc[j]);
        o[j] = q;
        float vr = bf2f(q);
        sl[j] = vr * vr;
    }
    *(u16x8*)(out + (size_t)z * HW * CH3 + (size_t)cg * HW * 8 + (size_t)px * 8) = o;

    if (c0 < 384) {   // q,k channels: accumulate sum-squares
        int wid = t >> 6, lane = t & 63;
#pragma unroll
        for (int j = 0; j < 8; ++j)
            for (int off = 32; off; off >>= 1) sl[j] += __shfl_down(sl[j], off);
        __shared__ float wr[4][8];
        if (lane == 0)
#pragma unroll
            for (int j = 0; j < 8; ++j) wr[wid][j] = sl[j];
        __syncthreads();
        if (t < 8) {
            float s = wr[0][t] + wr[1][t] + wr[2][t] + wr[3][t];
            atomicAdd(&ssbuf[z * 384 + c0 + t], s);
        }
    }
}

// ---------------------------------------------------------------------------
// Gram partials: G[cq][ck] = sum_p q[p][cq]*k[p][ck] per 128-px slice.
// LDS transpose-stage C8 -> [c][p], then MFMA (waves split p). grid (128,4,Z)
// ---------------------------------------------------------------------------
__global__ __launch_bounds__(256) void gram1(const unsigned short* __restrict__ qkvT,
                                             float* __restrict__ G0p) {
    const int sl = blockIdx.x, hh = blockIdx.y, z = blockIdx.z;
    const int t = threadIdx.x;
    const int wid = t >> 6, lane = t & 63, lm = lane & 15, quad = lane >> 4;

    __shared__ float Gs[4][2304];                       // 36.9 KB, aliased below
    unsigned short* qs = (unsigned short*)&Gs[0][0];    // [48][LDP]
    unsigned short* ks = qs + 48 * LDP;

    const unsigned short* bz = qkvT + (size_t)z * HW * CH3;
    int half = t & 1, pl = t >> 1;
    size_t pofs = (size_t)(sl * 128 + pl) * 8;
#pragma unroll
    for (int ci = 0; ci < 3; ++ci) {
        int cg = half * 3 + ci;                          // 0..5 within head
        u16x8 uq = *(const u16x8*)(bz + (size_t)(hh * 6 + cg) * HW * 8 + pofs);
        u16x8 uk = *(const u16x8*)(bz + (size_t)(24 + hh * 6 + cg) * HW * 8 + pofs);
#pragma unroll
        for (int j = 0; j < 8; ++j) {
            qs[(cg * 8 + j) * LDP + pl] = uq[j];
            ks[(cg * 8 + j) * LDP + pl] = uk[j];
        }
    }
    __syncthreads();

    v4f acc[3][3];
#pragma unroll
    for (int mi = 0; mi < 3; ++mi)
#pragma unroll
        for (int ni = 0; ni < 3; ++ni) acc[mi][ni] = (v4f)0.0f;

    int kp = wid * 32;    // each wave one p-quarter
    v8s a[3], b[3];
#pragma unroll
    for (int i = 0; i < 3; ++i) {
        a[i] = *(const v8s*)&qs[(i * 16 + lm) * LDP + kp + quad * 8];
        b[i] = *(const v8s*)&ks[(i * 16 + lm) * LDP + kp + quad * 8];
    }
#pragma unroll
    for (int mi = 0; mi < 3; ++mi)
#pragma unroll
        for (int ni = 0; ni < 3; ++ni)
            acc[mi][ni] = __builtin_amdgcn_mfma_f32_16x16x32_bf16(a[mi], b[ni], acc[mi][ni], 0, 0, 0);

    __syncthreads();   // staged data consumed; safe to overwrite with Gs
#pragma unroll
    for (int mi = 0; mi < 3; ++mi)
#pragma unroll
        for (int ni = 0; ni < 3; ++ni)
#pragma unroll
            for (int r = 0; r < 4; ++r)
                Gs[wid][(mi * 16 + quad * 4 + r) * 48 + ni * 16 + lm] = acc[mi][ni][r];
    __syncthreads();
    float* gp = G0p + (((size_t)z * NHEADS + hh) * NSL2 + sl) * 2304;
    for (int i = t; i < 2304; i += 256)
        gp[i] = Gs[0][i] + Gs[1][i] + Gs[2][i] + Gs[3][i];
}

// ---------------------------------------------------------------------------
// softmax over d with inline inv-norms; outputs bf16 A zero-padded [48][64].
// grid (4, Z) x 256
// ---------------------------------------------------------------------------
__global__ __launch_bounds__(256) void softmax1(const float* __restrict__ G0p,
                                                const float* __restrict__ ssbuf,
                                                const float* __restrict__ temp,
                                                unsigned short* __restrict__ Apad) {
    int hh = blockIdx.x, z = blockIdx.y, t = threadIdx.x;
    __shared__ float Gsum[2304];
    const float* gb = G0p + ((size_t)z * NHEADS + hh) * NSL2 * 2304;
    for (int i = t; i < 2304; i += 256) {
        float s = 0.f;
#pragma unroll 8
        for (int sl = 0; sl < NSL2; ++sl) s += gb[(size_t)sl * 2304 + i];
        Gsum[i] = s;
    }
    __syncthreads();
    if (t < 48) {
        float T = temp[hh];
        const float* sb = ssbuf + z * 384;
        float invq = 1.0f / fmaxf(sqrtf(sb[hh * CHH + t]), 1e-12f);
        float lg[48];
        float mx = -1e30f;
#pragma unroll
        for (int d = 0; d < 48; ++d) {
            float invk = 1.0f / fmaxf(sqrtf(sb[192 + hh * CHH + d]), 1e-12f);
            float l = T * Gsum[t * 48 + d] * invq * invk;
            lg[d] = l;
            mx = fmaxf(mx, l);
        }
        float sum = 0.f;
#pragma unroll
        for (int d = 0; d < 48; ++d) { float e = expf(lg[d] - mx); lg[d] = e; sum += e; }
        float inv = 1.0f / sum;
        unsigned short* ap = Apad + ((size_t)z * NHEADS + hh) * 48 * 64 + t * 64;
#pragma unroll
        for (int d = 0; d < 48; ++d) ap[d] = f2bf(lg[d] * inv);
#pragma unroll
        for (int d = 48; d < 64; ++d) ap[d] = 0;
    }
}

// ---------------------------------------------------------------------------
// PV apply via MFMA: out[p][c] = sum_d V[p][d]*A[c][d]. V C8 direct (chunk
// clamped for the zero-padded k=48..63 -> finite junk x 0); A bf16 [48][64].
// grid (64, 4, Z)
// ---------------------------------------------------------------------------
__global__ __launch_bounds__(256) void apply_pv(const unsigned short* __restrict__ qkvT,
                                                const unsigned short* __restrict__ Apad,
                                                unsigned short* __restrict__ attnout) {
    const int t = threadIdx.x;
    const int hh = blockIdx.y, z = blockIdx.z;
    const int wid = t >> 6, lane = t & 63, lm = lane & 15, quad = lane >> 4;
    const int p0 = blockIdx.x * 256 + wid * 64;

    const unsigned short* bz = qkvT + (size_t)z * HW * CH3;
    const unsigned short* Ab = Apad + ((size_t)z * NHEADS + hh) * 48 * 64;

    v4f acc[4][3];
#pragma unroll
    for (int i = 0; i < 4; ++i)
#pragma unroll
        for (int j = 0; j < 3; ++j) acc[i][j] = (v4f)0.0f;

#pragma unroll
    for (int ks = 0; ks < 2; ++ks) {
        int cgv = 48 + hh * 6 + ks * 4 + quad;     // V chunk; >head range when k>=48
        if (cgv > 71) cgv = 71;                     // clamp: finite junk x A-pad zeros
        const unsigned short* vp = bz + (size_t)cgv * HW * 8;
        v8s a[4], b[3];
#pragma unroll
        for (int i = 0; i < 4; ++i)
            a[i] = *(const v8s*)(vp + (size_t)(p0 + i * 16 + lm) * 8);
#pragma unroll
        for (int j = 0; j < 3; ++j)
            b[j] = *(const v8s*)(Ab + (j * 16 + lm) * 64 + ks * 32 + quad * 8);
#pragma unroll
        for (int i = 0; i < 4; ++i)
#pragma unroll
            for (int j = 0; j < 3; ++j)
                acc[i][j] = __builtin_amdgcn_mfma_f32_16x16x32_bf16(a[i], b[j], acc[i][j], 0, 0, 0);
    }

    unsigned short* Oz = attnout + (size_t)z * HW * CDIM;
#pragma unroll
    for (int i = 0; i < 4; ++i)
#pragma unroll
        for (int j = 0; j < 3; ++j) {
            int ch = hh * CHH + j * 16 + lm;
            int cg = ch >> 3, co = ch & 7;
#pragma unroll
            for (int r = 0; r < 4; ++r) {
                int p = p0 + i * 16 + quad * 4 + r;
                Oz[(size_t)cg * HW * 8 + (size_t)p * 8 + co] = f2bf(acc[i][j][r]);
            }
        }
}

// ---------------------------------------------------------------------------
// FFN grouped 3x3 (192->576) C8: 1 input chunk -> 3 output chunks per thread.
// grid (64, 24, Z)
// ---------------------------------------------------------------------------
__global__ __launch_bounds__(256) void dw1_c8(const unsigned short* __restrict__ xn,
                                              const unsigned short* __restrict__ wT,
                                              const float* __restrict__ b1,
                                              unsigned short* __restrict__ f1) {
    int t = threadIdx.x;
    int px = blockIdx.x * 256 + t;
    int gin = blockIdx.y;            // input chunk 0..23
    int c0 = gin * 24;               // first of 24 output channels
    int z = blockIdx.z;
    int h = px >> 7, w = px & 127;
    const unsigned short* ip = xn + (size_t)z * HW * CDIM + (size_t)gin * HW * 8;
    float acc[24];
#pragma unroll
    for (int j = 0; j < 24; ++j) acc[j] = b1[c0 + j];
#pragma unroll
    for (int ky = 0; ky < 3; ++ky) {
        int hy = h + ky - 1;
        if ((unsigned)hy >= 128u) continue;
#pragma unroll
        for (int kx = 0; kx < 3; ++kx) {
            int wx = w + kx - 1;
            if ((unsigned)wx >= 128u) continue;
            u16x8 xv = *(const u16x8*)(ip + (size_t)((hy << 7) + wx) * 8);
            float mv[8];
#pragma unroll
            for (int j = 0; j < 8; ++j) mv[j] = bf2f(xv[j]);
            const unsigned short* wp = wT + (ky * 3 + kx) * CH3 + c0;
            u16x8 w0 = *(const u16x8*)wp;
            u16x8 w1 = *(const u16x8*)(wp + 8);
            u16x8 w2 = *(const u16x8*)(wp + 16);
            float wv[24];
#pragma unroll
            for (int j = 0; j < 8; ++j) {
                wv[j] = bf2f(w0[j]); wv[8 + j] = bf2f(w1[j]); wv[16 + j] = bf2f(w2[j]);
            }
#pragma unroll
            for (int j = 0; j < 24; ++j) acc[j] = fmaf(wv[j], mv[j / 3], acc[j]);
        }
    }
    unsigned short* f1z = f1 + (size_t)z * HW * CH3;
#pragma unroll
    for (int q8 = 0; q8 < 3; ++q8) {
        u16x8 o;
#pragma unroll
        for (int j = 0; j < 8; ++j) o[j] = f2bf(acc[q8 * 8 + j]);
        *(u16x8*)(f1z + (size_t)(gin * 3 + q8) * HW * 8 + (size_t)px * 8) = o;
    }
}

// ---------------------------------------------------------------------------
// Depthwise 3x3 C8 576ch (FFN dw2). grid (64, 72, Z)
// ---------------------------------------------------------------------------
__global__ __launch_bounds__(256) void dw2_c8(const unsigned short* __restrict__ in,
                                              const unsigned short* __restrict__ wT,
                                              const float* __restrict__ b1,
                                              unsigned short* __restrict__ out) {
    int t = threadIdx.x;
    int px = blockIdx.x * 256 + t;
    int cg = blockIdx.y, c0 = cg * 8;
    int z = blockIdx.z;
    int h = px >> 7, w = px & 127;
    const unsigned short* ip = in + (size_t)z * HW * CH3 + (size_t)cg * HW * 8;
    float acc[8];
#pragma unroll
    for (int j = 0; j < 8; ++j) acc[j] = b1[c0 + j];
#pragma unroll
    for (int ky = 0; ky < 3; ++ky) {
        int hy = h + ky - 1;
        if ((unsigned)hy >= 128u) continue;
#pragma unroll
        for (int kx = 0; kx < 3; ++kx) {
            int wx = w + kx - 1;
            if ((unsigned)wx >= 128u) continue;
            u16x8 xv = *(const u16x8*)(ip + (size_t)((hy << 7) + wx) * 8);
            u16x8 wv = *(const u16x8*)(wT + (ky * 3 + kx) * CH3 + c0);
#pragma unroll
            for (int j = 0; j < 8; ++j) acc[j] = fmaf(bf2f(wv[j]), bf2f(xv[j]), acc[j]);
        }
    }
    u16x8 o;
#pragma unroll
    for (int j = 0; j < 8; ++j) o[j] = f2bf(acc[j]);
    *(u16x8*)(out + (size_t)z * HW * CH3 + (size_t)cg * HW * 8 + (size_t)px * 8) = o;
}

// ---------------------------------------------------------------------------
extern "C" void kernel_launch(void* const* d_in, const int* in_sizes, int n_in,
                              void* d_out, int out_size, void* d_ws, size_t ws_size,
                              hipStream_t stream) {
    const float* x      = (const float*)d_in[0];
    const float* ln1w   = (const float*)d_in[1];
    const float* ln1b   = (const float*)d_in[2];
    const float* qkv_w  = (const float*)d_in[3];
    const float* qkv_b  = (const float*)d_in[4];
    const float* qdw_w  = (const float*)d_in[5];
    const float* qdw_b  = (const float*)d_in[6];
    const float* temp   = (const float*)d_in[7];
    const float* prompt = (const float*)d_in[8];
    const float* proj_w = (const float*)d_in[9];
    const float* proj_b = (const float*)d_in[10];
    const float* ln2w   = (const float*)d_in[11];
    const float* ln2b   = (const float*)d_in[12];
    const float* dw1_w  = (const float*)d_in[13];
    const float* dw1_b  = (const float*)d_in[14];
    const float* pm_w   = (const float*)d_in[15];
    const float* pm_b   = (const float*)d_in[16];
    const float* dw2_w  = (const float*)d_in[17];
    const float* dw2_b  = (const float*)d_in[18];
    const float* po_w   = (const float*)d_in[19];
    const float* po_b   = (const float*)d_in[20];
    float* out = (float*)d_out;
    (void)in_sizes; (void)n_in; (void)out_size;

    const int NWQ = CH3 * CDIM, NWP = CDIM * CDIM, NWM = CH3 * CH3, NWO = CDIM * CH3;
    const int NWALL = NWQ + NWP + NWM + NWO;

    auto al = [](size_t b) { return (b + 255) & ~(size_t)255; };
    auto need = [&](int PG) -> size_t {
        return 2 * al((size_t)PG * HW * CH3 * 2)              // regionA, regionB
             + al((size_t)PG * HW * CDIM * 2)                  // xn / G0p union
             + al((size_t)PG * NHEADS * 48 * 64 * 2)           // Apad
             + al((size_t)PG * 384 * 4)                        // ssbuf
             + al((size_t)(NWALL + 3 * 9 * CH3) * 2) + 4096;
    };
    int PG = 8;
    while (PG > 1 && need(PG) > ws_size) PG >>= 1;

    size_t off = 0;
    char* base = (char*)d_ws;
    auto alloc = [&](size_t bytes) -> char* {
        char* p = base + off;
        off = (off + bytes + 255) & ~(size_t)255;
        return p;
    };
    unsigned short* regionA = (unsigned short*)alloc((size_t)PG * HW * CH3 * 2);
    unsigned short* regionB = (unsigned short*)alloc((size_t)PG * HW * CH3 * 2);
    unsigned short* xng     = (unsigned short*)alloc((size_t)PG * HW * CDIM * 2);
    unsigned short* Apad    = (unsigned short*)alloc((size_t)PG * NHEADS * 48 * 64 * 2);
    float*          ssbuf   = (float*)alloc((size_t)PG * 384 * 4);
    unsigned short* wbf     = (unsigned short*)alloc((size_t)(NWALL + 3 * 9 * CH3) * 2);

    unsigned short* wq   = wbf;
    unsigned short* wpj  = wbf + NWQ;
    unsigned short* wpm  = wbf + NWQ + NWP;
    unsigned short* wpo  = wbf + NWQ + NWP + NWM;
    unsigned short* wdwT = wbf + NWALL;
    unsigned short* wd1T = wdwT + 9 * CH3;
    unsigned short* wd2T = wd1T + 9 * CH3;

    unsigned short* preQKV  = regionA;   // attn: C8 [z][72][HW][8]
    unsigned short* attnout = regionA;   // C8 [z][24][HW][8] (preQKV dead)
    unsigned short* f1      = regionA;   // ffn C8
    unsigned short* f3      = regionA;   // aliases f1 (dead after pm)
    unsigned short* qkvT    = regionB;
    unsigned short* f2      = regionB;
    float* G0p = (float*)xng;            // aliases xn (dead after qkv GEMM)

    dim3 blk(256);

    wcvt<<<dim3(162, 7), blk, 0, stream>>>(qkv_w, proj_w, pm_w, po_w,
                                           qdw_w, dw1_w, dw2_w,
                                           wbf, NWQ, NWP, NWM, NWO);

    for (int b0 = 0; b0 < NB; b0 += PG) {
        const float* xb = x + (size_t)b0 * CDIM * HW;
        float* x2b      = out + (size_t)b0 * CDIM * HW;

        // ---------- attention ----------
        zero_f<<<dim3((PG * 384 + 255) / 256), blk, 0, stream>>>(ssbuf, PG * 384);
        ln_norm<<<dim3(64, PG), blk, 0, stream>>>(xb, ln1w, ln1b, xng);
        gemm_c8<0, CDIM><<<dim3(128, 3, PG), blk, 0, stream>>>(
            wq, xng, qkv_b, preQKV);
        dwp_c8<<<dim3(64, 72, PG), blk, 0, stream>>>(
            preQKV, wdwT, qdw_b, prompt, qkvT, ssbuf);
        gram1<<<dim3(NSL2, NHEADS, PG), blk, 0, stream>>>(qkvT, G0p);
        softmax1<<<dim3(NHEADS, PG), blk, 0, stream>>>(G0p, ssbuf, temp, Apad);
        apply_pv<<<dim3(64, NHEADS, PG), blk, 0, stream>>>(qkvT, Apad, attnout);
        gemm_nchw<CDIM><<<dim3(128, 1, PG), blk, 0, stream>>>(
            wpj, attnout, proj_b, xb, x2b);

        // ---------- FFN ----------
        ln_norm<<<dim3(64, PG), blk, 0, stream>>>(x2b, ln2w, ln2b, xng);
        dw1_c8<<<dim3(64, 24, PG), blk, 0, stream>>>(xng, wd1T, dw1_b, f1);
        gemm_c8<1, CH3><<<dim3(128, 3, PG), blk, 0, stream>>>(
            wpm, f1, pm_b, f2);
        dw2_c8<<<dim3(64, 72, PG), blk, 0, stream>>>(f2, wd2T, dw2_b, f3);
        gemm_nchw<CH3><<<dim3(128, 1, PG), blk, 0, stream>>>(
            wpo, f3, po_b, x2b, x2b);
    }
}